// Round 14
// baseline (1260.425 us; speedup 1.0000x reference)
//
#include <hip/hip_runtime.h>
#include <cstdint>
#include <cstddef>

// ---------------------------------------------------------------------------
// GCN(1 layer, sym-norm w/ self loops) -> LSTM(1 layer, T=9) -> FC, eval mode
// Round 14: round-13 plan with the nontemporal-load compile fix (csr entry
// loaded as long long — HIP_vector_type not accepted by the builtin).
// xw_all [N][T][H] (edge's 9 source rows contiguous), emb_all written
// nontemporal (no L3 write-allocate) -> gather set stays L3-resident.
// ---------------------------------------------------------------------------

constexpr int N    = 50000;
constexpr int NP   = 50048;  // padded to 128-row strips (391*128)
constexpr int E    = 1600000;
constexpr int T    = 9;
constexpr int H    = 128;    // F_IN == H == 128
constexpr int G    = 512;    // 4*H (gates i,f,g,o)
constexpr int OUTD = 32;

constexpr int SCAN_CH = 512;
constexpr int NCH = (N + SCAN_CH - 1) / SCAN_CH;   // 98

// gates grid: 391 row-strips x 4 col-quarters
constexpr int GNWG = (NP / 128) * 4;               // 1564
constexpr int GQQ  = GNWG / 8;                     // 195
constexpr int GRR  = GNWG % 8;                     // 4

typedef __attribute__((ext_vector_type(8))) _Float16 f16x8;
typedef __attribute__((ext_vector_type(4))) float f32x4;
typedef __attribute__((ext_vector_type(4))) _Float16 f16x4;

// async global->LDS, 16B per lane; LDS dest = wave-uniform base + lane*16
__device__ __forceinline__ void gll16(const void* g, void* l) {
  __builtin_amdgcn_global_load_lds(
      (const __attribute__((address_space(1))) void*)g,
      (__attribute__((address_space(3))) void*)l, 16, 0, 0);
}

// ---------------- degree / CSR build ----------------

__global__ void k_count(const int* __restrict__ col, int* __restrict__ cnt) {
  int e = blockIdx.x * 256 + threadIdx.x;
  if (e < E) atomicAdd(&cnt[col[e]], 1);
}

__global__ void k_dinv(const int* __restrict__ cnt, float* __restrict__ dinv) {
  int v = blockIdx.x * 256 + threadIdx.x;
  if (v < N) dinv[v] = rsqrtf((float)cnt[v] + 1.0f);   // +1 self loop
}

__global__ void k_chunk_sum(const int* __restrict__ cnt, int* __restrict__ csum) {
  __shared__ int sp[SCAN_CH / 64];
  int i = blockIdx.x * SCAN_CH + threadIdx.x;
  int v = (i < N) ? cnt[i] : 0;
  for (int off = 32; off > 0; off >>= 1) v += __shfl_down(v, off, 64);
  if ((threadIdx.x & 63) == 0) sp[threadIdx.x >> 6] = v;
  __syncthreads();
  if (threadIdx.x == 0) {
    int s = 0;
    #pragma unroll
    for (int w = 0; w < SCAN_CH / 64; ++w) s += sp[w];
    csum[blockIdx.x] = s;
  }
}

__global__ void k_chunk_scan(const int* __restrict__ csum, int* __restrict__ coff) {
  if (blockIdx.x == 0 && threadIdx.x == 0) {
    int run = 0;
    for (int b = 0; b < NCH; ++b) { coff[b] = run; run += csum[b]; }
    coff[NCH] = run;
  }
}

__global__ void k_scan_final(const int* __restrict__ cnt, const int* __restrict__ coff,
                             int* __restrict__ offv) {
  __shared__ int s[SCAN_CH];
  int tid = threadIdx.x;
  int i = blockIdx.x * SCAN_CH + tid;
  int v = (i < N) ? cnt[i] : 0;
  s[tid] = v;
  __syncthreads();
  for (int st = 1; st < SCAN_CH; st <<= 1) {
    int tv = (tid >= st) ? s[tid - st] : 0;
    __syncthreads();
    s[tid] += tv;
    __syncthreads();
  }
  if (i < N) offv[i] = coff[blockIdx.x] + s[tid] - v;   // exclusive
  if (blockIdx.x == 0 && tid == 0) offv[N] = coff[NCH];
}

// packed CSR entry: one 8B scatter per edge (halves write amplification)
__global__ void k_fill(const int* __restrict__ row, const int* __restrict__ col,
                       const float* __restrict__ dinv, const int* __restrict__ offv,
                       int* __restrict__ cursor, int2* __restrict__ csr) {
  int e = blockIdx.x * 256 + threadIdx.x;
  if (e >= E) return;
  int r = row[e], c = col[e];
  int p = atomicAdd(&cursor[c], 1);
  float nm = dinv[r] * dinv[c];
  csr[offv[c] + p] = make_int2(r, __builtin_bit_cast(int, nm));
}

// ---------------- weight prep (once per call) ----------------
// LSTM: bt[j][k] fp16 (j<512, k<256): k<128 -> W_ih[j][k], else W_hh[j][k-128]
__global__ void k_wprep_lstm(const float* __restrict__ Wih, const float* __restrict__ Whh,
                             _Float16* __restrict__ bt) {
  int idx = blockIdx.x * 256 + threadIdx.x;   // 512*256
  if (idx >= G * 256) return;
  int j = idx >> 8, k = idx & 255;
  float f = (k < H) ? Wih[j * H + k] : Whh[j * H + (k - H)];
  bt[idx] = (_Float16)f;
}

// GCN: bgT[j][k] = W_gcn[k][j]  (128x128) fp16
__global__ void k_wprep_gcn(const float* __restrict__ Wg, _Float16* __restrict__ bgT) {
  int idx = blockIdx.x * 256 + threadIdx.x;   // 128*128
  if (idx >= H * H) return;
  int j = idx >> 7, k = idx & 127;
  bgT[idx] = (_Float16)Wg[k * H + j];
}

// FC: wfc16[j][k] fp16 copy of W_fc (32x128)
__global__ void k_wprep_fc(const float* __restrict__ Wfc, _Float16* __restrict__ w16) {
  int idx = blockIdx.x * 256 + threadIdx.x;   // 32*128
  if (idx < OUTD * H) w16[idx] = (_Float16)Wfc[idx];
}

// ---------------- GCN GEMM (MFMA fp16), ALL timesteps ----------------
// xw_all layout [N][T][H]: row n, plane t at offset (n*T + t)*H.
// grid (391, 9); block 256 thr = 4 waves (2x2) -> 128 rows x 128 cols.
__global__ __launch_bounds__(256) void k_gcn_all(const float* __restrict__ Xall,
                                                 const _Float16* __restrict__ BgT,
                                                 _Float16* __restrict__ xw_all) {
  __shared__ _Float16 lsB[16384];   // [kb][j][g'] 16B granules, 32KB
  const float* X = Xall + (size_t)blockIdx.y * N * H;
  _Float16* xw = xw_all + (size_t)blockIdx.y * H;   // plane t offset within row
  int tid = threadIdx.x;
  int lane = tid & 63, wid = tid >> 6;
  int wr = wid >> 1, wc = wid & 1;
  int rb = blockIdx.x * 128 + wr * 64;
  int cb = wc * 64;
  int lr = lane & 15;
  int g  = lane >> 4;

  #pragma unroll
  for (int i = 0; i < 8; ++i) {           // stage B: 2048 granules of 16B
    int c = i * 256 + tid;
    int kb = c >> 9, j = (c >> 2) & 127, gg = c & 3;
    f16x8 v = *(const f16x8*)&BgT[j * H + kb * 32 + gg * 8];
    int slot = gg ^ ((j >> 1) & 3);
    *(f16x8*)&lsB[kb * 4096 + j * 32 + slot * 8] = v;
  }
  __syncthreads();

  f32x4 acc[4][4];
  #pragma unroll
  for (int mi = 0; mi < 4; ++mi)
    #pragma unroll
    for (int ni = 0; ni < 4; ++ni) acc[mi][ni] = (f32x4)0.0f;

  #pragma unroll
  for (int kb = 0; kb < 4; ++kb) {
    f16x8 bfr[4];
    #pragma unroll
    for (int ni = 0; ni < 4; ++ni) {
      int j = cb + ni * 16 + lr;
      bfr[ni] = *(const f16x8*)&lsB[kb * 4096 + j * 32 + (g ^ ((j >> 1) & 3)) * 8];
    }
    #pragma unroll
    for (int mi = 0; mi < 4; ++mi) {
      int r = rb + mi * 16 + lr;
      r = r < N ? r : N - 1;                     // clamp (pad rows discarded)
      const float* ap = X + (size_t)r * H + kb * 32 + g * 8;
      float4 a0 = *(const float4*)ap;
      float4 a1 = *(const float4*)(ap + 4);
      f16x8 afr;
      afr[0] = (_Float16)a0.x; afr[1] = (_Float16)a0.y;
      afr[2] = (_Float16)a0.z; afr[3] = (_Float16)a0.w;
      afr[4] = (_Float16)a1.x; afr[5] = (_Float16)a1.y;
      afr[6] = (_Float16)a1.z; afr[7] = (_Float16)a1.w;
      #pragma unroll
      for (int ni = 0; ni < 4; ++ni)
        acc[mi][ni] = __builtin_amdgcn_mfma_f32_16x16x32_f16(afr, bfr[ni], acc[mi][ni], 0, 0, 0);
    }
  }
  int orow = (lane >> 4) * 4;
  #pragma unroll
  for (int mi = 0; mi < 4; ++mi)
    #pragma unroll
    for (int ni = 0; ni < 4; ++ni)
      #pragma unroll
      for (int r = 0; r < 4; ++r) {
        int n = rb + mi * 16 + orow + r;
        if (n < N) xw[(size_t)n * (T * H) + cb + ni * 16 + lr] = (_Float16)acc[mi][ni][r];
      }
}

// ---------------- aggregation, ALL timesteps in one dispatch ----------------
// Wave per vertex; two 32-lane halves process even/odd edges. Edge metadata
// read ONCE (nontemporal, as long long), then 9 gathers from the CONTIGUOUS
// 2304B source region (xw_all [N][T][H]). emb written NONTEMPORAL (no L3
// write-allocate) to emb_all[t][N][128].
__global__ __launch_bounds__(256) void k_agg_all(const _Float16* __restrict__ xw_all,
                                                 const int* __restrict__ offv,
                                                 const long long* __restrict__ csr,
                                                 const float* __restrict__ dinv,
                                                 const float* __restrict__ bg,
                                                 _Float16* __restrict__ emb_all) {
  int wid = threadIdx.x >> 6, lane = threadIdx.x & 63;
  int v = blockIdx.x * 4 + wid;          // N % 4 == 0
  int half = lane >> 5, sl = lane & 31;
  int c0 = sl * 4;
  float acc[T][4];
  #pragma unroll
  for (int t = 0; t < T; ++t) {
    acc[t][0] = 0.f; acc[t][1] = 0.f; acc[t][2] = 0.f; acc[t][3] = 0.f;
  }
  if (half == 0) {                       // self term once
    float dv = dinv[v];
    float w = dv * dv;
    const _Float16* xp = xw_all + (size_t)v * (T * H) + c0;
    #pragma unroll
    for (int t = 0; t < T; ++t) {
      f16x4 xs = *(const f16x4*)(xp + t * H);
      acc[t][0] = (float)xs.x * w; acc[t][1] = (float)xs.y * w;
      acc[t][2] = (float)xs.z * w; acc[t][3] = (float)xs.w * w;
    }
  }
  int e0 = offv[v], e1 = offv[v + 1];
  for (int e = e0 + half; e < e1; e += 2) {
    long long raw = __builtin_nontemporal_load(&csr[e]);
    int s = (int)(raw & 0xffffffffLL);
    float m = __builtin_bit_cast(float, (int)(raw >> 32));
    const _Float16* xp = xw_all + (size_t)s * (T * H) + c0;
    #pragma unroll
    for (int t = 0; t < T; ++t) {
      f16x4 x = *(const f16x4*)(xp + t * H);
      acc[t][0] = fmaf((float)x.x, m, acc[t][0]);
      acc[t][1] = fmaf((float)x.y, m, acc[t][1]);
      acc[t][2] = fmaf((float)x.z, m, acc[t][2]);
      acc[t][3] = fmaf((float)x.w, m, acc[t][3]);
    }
  }
  #pragma unroll
  for (int t = 0; t < T; ++t) {
    acc[t][0] += __shfl_xor(acc[t][0], 32, 64);
    acc[t][1] += __shfl_xor(acc[t][1], 32, 64);
    acc[t][2] += __shfl_xor(acc[t][2], 32, 64);
    acc[t][3] += __shfl_xor(acc[t][3], 32, 64);
  }
  if (half == 0) {
    float4 bb = *(const float4*)&bg[c0];
    #pragma unroll
    for (int t = 0; t < T; ++t) {
      f16x4 ov;
      ov.x = (_Float16)fmaxf(acc[t][0] + bb.x, 0.f);
      ov.y = (_Float16)fmaxf(acc[t][1] + bb.y, 0.f);
      ov.z = (_Float16)fmaxf(acc[t][2] + bb.z, 0.f);
      ov.w = (_Float16)fmaxf(acc[t][3] + bb.w, 0.f);
      __builtin_nontemporal_store(ov,
          (f16x4*)&emb_all[(size_t)t * N * H + (size_t)v * H + c0]);
    }
  }
}

// ---------------- fused gates GEMM + LSTM cell (fp16, global_load_lds) ------
// 256 thr = 4 waves (wr x wc = 2x2). Block tile: 128 rows x 128 logical cols
// (jj = gate*32 + wc*16 + lr -> global j = gate*128 + ch0 + ...), so each wave
// holds (i,f,g,o) of the same (row, channel): cell update in-register.
// K: 8 kblocks of 32 fp16 — kb 0..3 stage emb_t[N][128], kb 4..7 stage
// h_{t-1}[N][128] (uniform branch). Double-buffered 2x16KB LDS via
// global_load_lds; granule swizzle slot = q ^ ((row>>1)&3) (2-way, free),
// applied by pre-swizzling the GLOBAL source granule (rule #21).
// h_t written to the compact fp16 oH[N][128] plane (ping-pong, no race).
template<bool FIRST>
__global__ __launch_bounds__(256) void k_gates_cell(const _Float16* __restrict__ embt,
                                                    const _Float16* __restrict__ hcur,
                                                    const _Float16* __restrict__ Bt,
                                                    const float* __restrict__ bih,
                                                    const float* __restrict__ bhh,
                                                    float* __restrict__ cbuf,
                                                    _Float16* __restrict__ oH) {
  __shared__ _Float16 ls[2][8192];   // 2 x 16KB: [A 8KB | B 8KB]
  const int tid = threadIdx.x;
  const int lane = tid & 63, wid = tid >> 6;
  const int wr = wid >> 1, wc = wid & 1;
  const int lr = lane & 15;
  const int g  = lane >> 4;                 // k granule 0..3 (8 fp16 each)

  // bijective XCD-chunk swizzle (m204)
  int xcd = blockIdx.x & 7, loc = blockIdx.x >> 3;
  int wgid = (xcd < GRR ? xcd * (GQQ + 1) : GRR * (GQQ + 1) + (xcd - GRR) * GQQ) + loc;
  const int rb  = (wgid >> 2) * 128;
  const int ch0 = (wgid & 3) * 32;

  f32x4 acc[4][4];
  #pragma unroll
  for (int mi = 0; mi < 4; ++mi)
    #pragma unroll
    for (int ni = 0; ni < 4; ++ni) acc[mi][ni] = (f32x4)0.0f;

  // stage one 16KB k-block tile (async, no data registers)
  auto stage = [&](int buf, int kb) {
    const _Float16* srcA = (kb < 4) ? embt : hcur;   // both [N(P)][128]
    int koA = (kb & 3) * 32;
    int koB = kb * 32;
    _Float16* lb = &ls[buf][0];
    #pragma unroll
    for (int i = 0; i < 2; ++i) {
      int c = i * 256 + tid;               // 16B chunk id 0..511
      int row = c >> 2, slot = c & 3;
      int g3 = slot ^ ((row >> 1) & 3);    // pre-swizzled global granule
      size_t ga = (size_t)(rb + row) * H + koA + g3 * 8;
      gll16(srcA + ga, lb + c * 8);
      int j = (row >> 5) * 128 + ch0 + (row & 31);
      size_t gb = (size_t)j * 256 + koB + g3 * 8;
      gll16(Bt + gb, lb + 4096 + c * 8);
    }
  };

  auto compute = [&](int buf) {
    const _Float16* lb = &ls[buf][0];
    f16x8 bfr[4];
    #pragma unroll
    for (int ni = 0; ni < 4; ++ni) {
      int jj = ni * 32 + wc * 16 + lr;
      bfr[ni] = *(const f16x8*)(lb + 4096 + jj * 32 + (g ^ ((jj >> 1) & 3)) * 8);
    }
    #pragma unroll
    for (int mi = 0; mi < 4; ++mi) {
      int rr = wr * 64 + mi * 16 + lr;
      f16x8 afr = *(const f16x8*)(lb + rr * 32 + (g ^ ((rr >> 1) & 3)) * 8);
      #pragma unroll
      for (int ni = 0; ni < 4; ++ni)
        acc[mi][ni] = __builtin_amdgcn_mfma_f32_16x16x32_f16(afr, bfr[ni], acc[mi][ni], 0, 0, 0);
    }
  };

  const int kbs = FIRST ? 4 : 8;            // t=0: h==0, skip upper K half
  stage(0, 0);
  for (int kb = 0; kb < kbs; ++kb) {
    __syncthreads();                        // buf[kb&1] staged; prev reads done
    if (kb + 1 < kbs) stage((kb + 1) & 1, kb + 1);  // async, hides under MFMAs
    compute(kb & 1);
  }

  int ch = ch0 + wc * 16 + lr;
  float bi_ = bih[ch]       + bhh[ch];
  float bf_ = bih[128 + ch] + bhh[128 + ch];
  float bg_ = bih[256 + ch] + bhh[256 + ch];
  float bo_ = bih[384 + ch] + bhh[384 + ch];
  int orow = (lane >> 4) * 4;
  int rbw = rb + wr * 64;
  #pragma unroll
  for (int mi = 0; mi < 4; ++mi) {
    #pragma unroll
    for (int r = 0; r < 4; ++r) {
      int n = rbw + mi * 16 + orow + r;
      if (n >= N) continue;
      float gi = acc[mi][0][r] + bi_;
      float gf = acc[mi][1][r] + bf_;
      float gg = acc[mi][2][r] + bg_;
      float go = acc[mi][3][r] + bo_;
      float si = 1.f / (1.f + expf(-gi));
      float sf = 1.f / (1.f + expf(-gf));
      float so = 1.f / (1.f + expf(-go));
      float tg = tanhf(gg);
      size_t ci = (size_t)n * H + ch;
      float cn = FIRST ? si * tg : fmaf(sf, cbuf[ci], si * tg);
      cbuf[ci] = cn;
      float hn = so * tanhf(cn);
      oH[ci] = (_Float16)hn;
    }
  }
}

// ---------------- FC (MFMA): out[n][t][:] = h[n] @ W_fc^T + b_fc ----------------
// h fp16 from compact plane [N][128]; Wfc fp16 [32][128]. Wave = 64 rows x 32
// cols (mi=4, ni=2, 4 kblocks -> 32 MFMAs). Block 256 thr = 4 waves = 256 rows.
__global__ __launch_bounds__(256) void k_fc_mfma(const _Float16* __restrict__ Hc,
                                                 const _Float16* __restrict__ w16,
                                                 const float* __restrict__ bfc,
                                                 float* __restrict__ outp, int t) {
  int lane = threadIdx.x & 63, wid = threadIdx.x >> 6;
  int rb = blockIdx.x * 256 + wid * 64;
  int lr = lane & 15, g = lane >> 4;
  f32x4 acc[4][2];
  #pragma unroll
  for (int mi = 0; mi < 4; ++mi) { acc[mi][0] = (f32x4)0.0f; acc[mi][1] = (f32x4)0.0f; }

  #pragma unroll
  for (int kb = 0; kb < 4; ++kb) {
    int ko = kb * 32 + g * 8;
    f16x8 bfr[2];
    #pragma unroll
    for (int ni = 0; ni < 2; ++ni)
      bfr[ni] = *(const f16x8*)&w16[(ni * 16 + lr) * H + ko];
    #pragma unroll
    for (int mi = 0; mi < 4; ++mi) {
      int n = rb + mi * 16 + lr;
      n = n < N ? n : N - 1;               // clamp (pad rows discarded)
      f16x8 afr = *(const f16x8*)&Hc[(size_t)n * H + ko];
      #pragma unroll
      for (int ni = 0; ni < 2; ++ni)
        acc[mi][ni] = __builtin_amdgcn_mfma_f32_16x16x32_f16(afr, bfr[ni], acc[mi][ni], 0, 0, 0);
    }
  }
  int orow = g * 4;
  #pragma unroll
  for (int ni = 0; ni < 2; ++ni) {
    int oc = ni * 16 + lr;
    float bb = bfc[oc];
    #pragma unroll
    for (int mi = 0; mi < 4; ++mi)
      #pragma unroll
      for (int r = 0; r < 4; ++r) {
        int n = rb + mi * 16 + orow + r;
        if (n < N) outp[((size_t)n * T + t) * OUTD + oc] = acc[mi][ni][r] + bb;
      }
  }
}

// ---------------------------------------------------------------------------

extern "C" void kernel_launch(void* const* d_in, const int* in_sizes, int n_in,
                              void* d_out, int out_size, void* d_ws, size_t ws_size,
                              hipStream_t stream) {
  const float* x_seq = (const float*)d_in[0];
  const int*   eidx  = (const int*)d_in[1];
  const int*   erow  = eidx;          // sources
  const int*   ecol  = eidx + E;      // targets
  const float* W_gcn = (const float*)d_in[2];
  const float* b_gcn = (const float*)d_in[3];
  const float* W_ih  = (const float*)d_in[4];
  const float* W_hh  = (const float*)d_in[5];
  const float* b_ih  = (const float*)d_in[6];
  const float* b_hh  = (const float*)d_in[7];
  const float* W_fc  = (const float*)d_in[8];
  const float* b_fc  = (const float*)d_in[9];
  float* outp = (float*)d_out;

  char* base = (char*)d_ws;
  size_t o = 0;
  auto alloc = [&](size_t bytes) -> void* {
    void* p = base + o;
    o += (bytes + 255) & ~(size_t)255;
    return p;
  };
  int*   cnt      = (int*)  alloc((size_t)N * 4);
  int*   cursor   = (int*)  alloc((size_t)N * 4);
  int*   offv     = (int*)  alloc((size_t)(N + 1) * 4);
  int*   csum     = (int*)  alloc((size_t)(NCH + 1) * 4);
  int*   coff     = (int*)  alloc((size_t)(NCH + 1) * 4);
  float* dinv     = (float*)alloc((size_t)N * 4);
  int2*  csr      = (int2*) alloc((size_t)E * 8);
  _Float16* bt    = (_Float16*)alloc((size_t)G * 256 * 2);
  _Float16* bgT   = (_Float16*)alloc((size_t)H * H * 2);
  _Float16* wfc16 = (_Float16*)alloc((size_t)OUTD * H * 2);
  _Float16* xw_all = (_Float16*)alloc((size_t)N * T * H * 2);        // [N][T][H], 115 MB
  _Float16* emb_all= (_Float16*)alloc((size_t)(T * N + 128) * H * 2); // [T][N][H] + pad
  _Float16* h0    = (_Float16*)alloc((size_t)NP * H * 2);            // compact h, even t
  _Float16* h1    = (_Float16*)alloc((size_t)NP * H * 2);            // odd t
  float* cbuf     = (float*)alloc((size_t)N * H * 4);
  (void)ws_size; (void)in_sizes; (void)n_in; (void)out_size;

  _Float16* HP[2] = {h0, h1};

  // only the small CSR counters need zeroing; h/c state handled by the
  // FIRST-step specialization; pad rows only affect discarded output rows.
  hipMemsetAsync(cnt,    0, (size_t)N * 4, stream);
  hipMemsetAsync(cursor, 0, (size_t)N * 4, stream);

  k_count<<<E / 256, 256, 0, stream>>>(ecol, cnt);
  k_dinv<<<(N + 255) / 256, 256, 0, stream>>>(cnt, dinv);
  k_chunk_sum<<<NCH, SCAN_CH, 0, stream>>>(cnt, csum);
  k_chunk_scan<<<1, 64, 0, stream>>>(csum, coff);
  k_scan_final<<<NCH, SCAN_CH, 0, stream>>>(cnt, coff, offv);
  k_fill<<<E / 256, 256, 0, stream>>>(erow, ecol, dinv, offv, cursor, csr);
  k_wprep_lstm<<<(G * 256) / 256, 256, 0, stream>>>(W_ih, W_hh, bt);
  k_wprep_gcn<<<(H * H) / 256, 256, 0, stream>>>(W_gcn, bgT);
  k_wprep_fc<<<(OUTD * H + 255) / 256, 256, 0, stream>>>(W_fc, wfc16);

  // all 9 GCN GEMMs in one dispatch (no LSTM dependence)
  k_gcn_all<<<dim3(NP / 128, T), 256, 0, stream>>>(x_seq, bgT, xw_all);
  // whole aggregation phase in one dispatch (meta read once, 9 gathers
  // from one contiguous source region; nontemporal emb writes)
  k_agg_all<<<N / 4, 256, 0, stream>>>(xw_all, offv, (const long long*)csr,
                                       dinv, b_gcn, emb_all);

  int fcblocks = (NP + 255) / 256;        // 196
  for (int t = 0; t < T; ++t) {
    int cur = t & 1, nxt = cur ^ 1;
    const _Float16* embt = emb_all + (size_t)t * N * H;
    if (t == 0)
      k_gates_cell<true><<<GNWG, 256, 0, stream>>>(
          embt, HP[cur], bt, b_ih, b_hh, cbuf, HP[nxt]);
    else
      k_gates_cell<false><<<GNWG, 256, 0, stream>>>(
          embt, HP[cur], bt, b_ih, b_hh, cbuf, HP[nxt]);
    k_fc_mfma<<<fcblocks, 256, 0, stream>>>(HP[nxt], wfc16, b_fc, outp, t);
  }
}

// Round 15
// 1255.001 us; speedup vs baseline: 1.0043x; 1.0043x over previous
//
#include <hip/hip_runtime.h>
#include <cstdint>
#include <cstddef>

// ---------------------------------------------------------------------------
// GCN(1 layer, sym-norm w/ self loops) -> LSTM(1 layer, T=9) -> FC, eval mode
// Round 15: aggregation t-chunked into 2 passes (t=0..4 and t=5..8) with
// per-chunk xw layout [N][TC*H] -> per-pass hot set 51-64MB (vs 243MB at the
// 256MB MALL capacity); edge loop unrolled x2 (8-10 loads in flight/lane).
// Tests the L3-capacity-thrash theory head-on. gates/fc/CSR unchanged.
// ---------------------------------------------------------------------------

constexpr int N    = 50000;
constexpr int NP   = 50048;  // padded to 128-row strips (391*128)
constexpr int E    = 1600000;
constexpr int T    = 9;
constexpr int H    = 128;    // F_IN == H == 128
constexpr int G    = 512;    // 4*H (gates i,f,g,o)
constexpr int OUTD = 32;
constexpr int TCA  = 5;      // chunk A: t = 0..4
constexpr int TCB  = 4;      // chunk B: t = 5..8

constexpr int SCAN_CH = 512;
constexpr int NCH = (N + SCAN_CH - 1) / SCAN_CH;   // 98

// gates grid: 391 row-strips x 4 col-quarters
constexpr int GNWG = (NP / 128) * 4;               // 1564
constexpr int GQQ  = GNWG / 8;                     // 195
constexpr int GRR  = GNWG % 8;                     // 4

typedef __attribute__((ext_vector_type(8))) _Float16 f16x8;
typedef __attribute__((ext_vector_type(4))) float f32x4;
typedef __attribute__((ext_vector_type(4))) _Float16 f16x4;

// async global->LDS, 16B per lane; LDS dest = wave-uniform base + lane*16
__device__ __forceinline__ void gll16(const void* g, void* l) {
  __builtin_amdgcn_global_load_lds(
      (const __attribute__((address_space(1))) void*)g,
      (__attribute__((address_space(3))) void*)l, 16, 0, 0);
}

// ---------------- degree / CSR build ----------------

__global__ void k_count(const int* __restrict__ col, int* __restrict__ cnt) {
  int e = blockIdx.x * 256 + threadIdx.x;
  if (e < E) atomicAdd(&cnt[col[e]], 1);
}

__global__ void k_dinv(const int* __restrict__ cnt, float* __restrict__ dinv) {
  int v = blockIdx.x * 256 + threadIdx.x;
  if (v < N) dinv[v] = rsqrtf((float)cnt[v] + 1.0f);   // +1 self loop
}

__global__ void k_chunk_sum(const int* __restrict__ cnt, int* __restrict__ csum) {
  __shared__ int sp[SCAN_CH / 64];
  int i = blockIdx.x * SCAN_CH + threadIdx.x;
  int v = (i < N) ? cnt[i] : 0;
  for (int off = 32; off > 0; off >>= 1) v += __shfl_down(v, off, 64);
  if ((threadIdx.x & 63) == 0) sp[threadIdx.x >> 6] = v;
  __syncthreads();
  if (threadIdx.x == 0) {
    int s = 0;
    #pragma unroll
    for (int w = 0; w < SCAN_CH / 64; ++w) s += sp[w];
    csum[blockIdx.x] = s;
  }
}

__global__ void k_chunk_scan(const int* __restrict__ csum, int* __restrict__ coff) {
  if (blockIdx.x == 0 && threadIdx.x == 0) {
    int run = 0;
    for (int b = 0; b < NCH; ++b) { coff[b] = run; run += csum[b]; }
    coff[NCH] = run;
  }
}

__global__ void k_scan_final(const int* __restrict__ cnt, const int* __restrict__ coff,
                             int* __restrict__ offv) {
  __shared__ int s[SCAN_CH];
  int tid = threadIdx.x;
  int i = blockIdx.x * SCAN_CH + tid;
  int v = (i < N) ? cnt[i] : 0;
  s[tid] = v;
  __syncthreads();
  for (int st = 1; st < SCAN_CH; st <<= 1) {
    int tv = (tid >= st) ? s[tid - st] : 0;
    __syncthreads();
    s[tid] += tv;
    __syncthreads();
  }
  if (i < N) offv[i] = coff[blockIdx.x] + s[tid] - v;   // exclusive
  if (blockIdx.x == 0 && tid == 0) offv[N] = coff[NCH];
}

// packed CSR entry: one 8B scatter per edge (halves write amplification)
__global__ void k_fill(const int* __restrict__ row, const int* __restrict__ col,
                       const float* __restrict__ dinv, const int* __restrict__ offv,
                       int* __restrict__ cursor, int2* __restrict__ csr) {
  int e = blockIdx.x * 256 + threadIdx.x;
  if (e >= E) return;
  int r = row[e], c = col[e];
  int p = atomicAdd(&cursor[c], 1);
  float nm = dinv[r] * dinv[c];
  csr[offv[c] + p] = make_int2(r, __builtin_bit_cast(int, nm));
}

// ---------------- weight prep (once per call) ----------------
// LSTM: bt[j][k] fp16 (j<512, k<256): k<128 -> W_ih[j][k], else W_hh[j][k-128]
__global__ void k_wprep_lstm(const float* __restrict__ Wih, const float* __restrict__ Whh,
                             _Float16* __restrict__ bt) {
  int idx = blockIdx.x * 256 + threadIdx.x;   // 512*256
  if (idx >= G * 256) return;
  int j = idx >> 8, k = idx & 255;
  float f = (k < H) ? Wih[j * H + k] : Whh[j * H + (k - H)];
  bt[idx] = (_Float16)f;
}

// GCN: bgT[j][k] = W_gcn[k][j]  (128x128) fp16
__global__ void k_wprep_gcn(const float* __restrict__ Wg, _Float16* __restrict__ bgT) {
  int idx = blockIdx.x * 256 + threadIdx.x;   // 128*128
  if (idx >= H * H) return;
  int j = idx >> 7, k = idx & 127;
  bgT[idx] = (_Float16)Wg[k * H + j];
}

// FC: wfc16[j][k] fp16 copy of W_fc (32x128)
__global__ void k_wprep_fc(const float* __restrict__ Wfc, _Float16* __restrict__ w16) {
  int idx = blockIdx.x * 256 + threadIdx.x;   // 32*128
  if (idx < OUTD * H) w16[idx] = (_Float16)Wfc[idx];
}

// ---------------- GCN GEMM (MFMA fp16), ALL timesteps ----------------
// Output into two chunk buffers: xwA [N][5*128] (t=0..4), xwB [N][4*128].
// grid (391, 9); block 256 thr = 4 waves (2x2) -> 128 rows x 128 cols.
__global__ __launch_bounds__(256) void k_gcn_all(const float* __restrict__ Xall,
                                                 const _Float16* __restrict__ BgT,
                                                 _Float16* __restrict__ xwA,
                                                 _Float16* __restrict__ xwB) {
  __shared__ _Float16 lsB[16384];   // [kb][j][g'] 16B granules, 32KB
  int t = blockIdx.y;
  const float* X = Xall + (size_t)t * N * H;
  _Float16* xw;
  int rs;
  if (t < TCA) { xw = xwA + t * H;         rs = TCA * H; }
  else         { xw = xwB + (t - TCA) * H; rs = TCB * H; }
  int tid = threadIdx.x;
  int lane = tid & 63, wid = tid >> 6;
  int wr = wid >> 1, wc = wid & 1;
  int rb = blockIdx.x * 128 + wr * 64;
  int cb = wc * 64;
  int lr = lane & 15;
  int g  = lane >> 4;

  #pragma unroll
  for (int i = 0; i < 8; ++i) {           // stage B: 2048 granules of 16B
    int c = i * 256 + tid;
    int kb = c >> 9, j = (c >> 2) & 127, gg = c & 3;
    f16x8 v = *(const f16x8*)&BgT[j * H + kb * 32 + gg * 8];
    int slot = gg ^ ((j >> 1) & 3);
    *(f16x8*)&lsB[kb * 4096 + j * 32 + slot * 8] = v;
  }
  __syncthreads();

  f32x4 acc[4][4];
  #pragma unroll
  for (int mi = 0; mi < 4; ++mi)
    #pragma unroll
    for (int ni = 0; ni < 4; ++ni) acc[mi][ni] = (f32x4)0.0f;

  #pragma unroll
  for (int kb = 0; kb < 4; ++kb) {
    f16x8 bfr[4];
    #pragma unroll
    for (int ni = 0; ni < 4; ++ni) {
      int j = cb + ni * 16 + lr;
      bfr[ni] = *(const f16x8*)&lsB[kb * 4096 + j * 32 + (g ^ ((j >> 1) & 3)) * 8];
    }
    #pragma unroll
    for (int mi = 0; mi < 4; ++mi) {
      int r = rb + mi * 16 + lr;
      r = r < N ? r : N - 1;                     // clamp (pad rows discarded)
      const float* ap = X + (size_t)r * H + kb * 32 + g * 8;
      float4 a0 = *(const float4*)ap;
      float4 a1 = *(const float4*)(ap + 4);
      f16x8 afr;
      afr[0] = (_Float16)a0.x; afr[1] = (_Float16)a0.y;
      afr[2] = (_Float16)a0.z; afr[3] = (_Float16)a0.w;
      afr[4] = (_Float16)a1.x; afr[5] = (_Float16)a1.y;
      afr[6] = (_Float16)a1.z; afr[7] = (_Float16)a1.w;
      #pragma unroll
      for (int ni = 0; ni < 4; ++ni)
        acc[mi][ni] = __builtin_amdgcn_mfma_f32_16x16x32_f16(afr, bfr[ni], acc[mi][ni], 0, 0, 0);
    }
  }
  int orow = (lane >> 4) * 4;
  #pragma unroll
  for (int mi = 0; mi < 4; ++mi)
    #pragma unroll
    for (int ni = 0; ni < 4; ++ni)
      #pragma unroll
      for (int r = 0; r < 4; ++r) {
        int n = rb + mi * 16 + orow + r;
        if (n < N) xw[(size_t)n * rs + cb + ni * 16 + lr] = (_Float16)acc[mi][ni][r];
      }
}

// ---------------- aggregation, one t-chunk per dispatch ----------------
// Wave per vertex; two 32-lane halves process even/odd edges, 2 edges per
// iteration (2*TC loads in flight). Edge meta read once per pass (NT).
// Source region [s][TC*H] contiguous (hot set = N*TC*256B, L3-resident).
template<int TC>
__global__ __launch_bounds__(256) void k_agg_chunk(const _Float16* __restrict__ xw,
                                                   const int* __restrict__ offv,
                                                   const long long* __restrict__ csr,
                                                   const float* __restrict__ dinv,
                                                   const float* __restrict__ bg,
                                                   _Float16* __restrict__ embc) {
  constexpr int RS = TC * H;
  int wid = threadIdx.x >> 6, lane = threadIdx.x & 63;
  int v = blockIdx.x * 4 + wid;          // N % 4 == 0
  int half = lane >> 5, sl = lane & 31;
  int c0 = sl * 4;
  float acc[TC][4];
  #pragma unroll
  for (int t = 0; t < TC; ++t) {
    acc[t][0] = 0.f; acc[t][1] = 0.f; acc[t][2] = 0.f; acc[t][3] = 0.f;
  }
  if (half == 0) {                       // self term once
    float dv = dinv[v];
    float w = dv * dv;
    const _Float16* xp = xw + (size_t)v * RS + c0;
    #pragma unroll
    for (int t = 0; t < TC; ++t) {
      f16x4 xs = *(const f16x4*)(xp + t * H);
      acc[t][0] = (float)xs.x * w; acc[t][1] = (float)xs.y * w;
      acc[t][2] = (float)xs.z * w; acc[t][3] = (float)xs.w * w;
    }
  }
  int e0 = offv[v], e1 = offv[v + 1];
  int e = e0 + half;
  for (; e + 2 < e1; e += 4) {           // 2 edges in flight per half
    long long r0 = __builtin_nontemporal_load(&csr[e]);
    long long r1 = __builtin_nontemporal_load(&csr[e + 2]);
    int s0 = (int)(r0 & 0xffffffffLL);
    int s1 = (int)(r1 & 0xffffffffLL);
    float m0 = __builtin_bit_cast(float, (int)(r0 >> 32));
    float m1 = __builtin_bit_cast(float, (int)(r1 >> 32));
    const _Float16* xp0 = xw + (size_t)s0 * RS + c0;
    const _Float16* xp1 = xw + (size_t)s1 * RS + c0;
    f16x4 xa[TC], xb[TC];
    #pragma unroll
    for (int t = 0; t < TC; ++t) {
      xa[t] = *(const f16x4*)(xp0 + t * H);
      xb[t] = *(const f16x4*)(xp1 + t * H);
    }
    #pragma unroll
    for (int t = 0; t < TC; ++t) {
      acc[t][0] = fmaf((float)xa[t].x, m0, acc[t][0]);
      acc[t][1] = fmaf((float)xa[t].y, m0, acc[t][1]);
      acc[t][2] = fmaf((float)xa[t].z, m0, acc[t][2]);
      acc[t][3] = fmaf((float)xa[t].w, m0, acc[t][3]);
      acc[t][0] = fmaf((float)xb[t].x, m1, acc[t][0]);
      acc[t][1] = fmaf((float)xb[t].y, m1, acc[t][1]);
      acc[t][2] = fmaf((float)xb[t].z, m1, acc[t][2]);
      acc[t][3] = fmaf((float)xb[t].w, m1, acc[t][3]);
    }
  }
  if (e < e1) {                          // tail edge
    long long r0 = __builtin_nontemporal_load(&csr[e]);
    int s0 = (int)(r0 & 0xffffffffLL);
    float m0 = __builtin_bit_cast(float, (int)(r0 >> 32));
    const _Float16* xp0 = xw + (size_t)s0 * RS + c0;
    #pragma unroll
    for (int t = 0; t < TC; ++t) {
      f16x4 x = *(const f16x4*)(xp0 + t * H);
      acc[t][0] = fmaf((float)x.x, m0, acc[t][0]);
      acc[t][1] = fmaf((float)x.y, m0, acc[t][1]);
      acc[t][2] = fmaf((float)x.z, m0, acc[t][2]);
      acc[t][3] = fmaf((float)x.w, m0, acc[t][3]);
    }
  }
  #pragma unroll
  for (int t = 0; t < TC; ++t) {
    acc[t][0] += __shfl_xor(acc[t][0], 32, 64);
    acc[t][1] += __shfl_xor(acc[t][1], 32, 64);
    acc[t][2] += __shfl_xor(acc[t][2], 32, 64);
    acc[t][3] += __shfl_xor(acc[t][3], 32, 64);
  }
  if (half == 0) {
    float4 bb = *(const float4*)&bg[c0];
    #pragma unroll
    for (int t = 0; t < TC; ++t) {
      f16x4 ov;
      ov.x = (_Float16)fmaxf(acc[t][0] + bb.x, 0.f);
      ov.y = (_Float16)fmaxf(acc[t][1] + bb.y, 0.f);
      ov.z = (_Float16)fmaxf(acc[t][2] + bb.z, 0.f);
      ov.w = (_Float16)fmaxf(acc[t][3] + bb.w, 0.f);
      __builtin_nontemporal_store(ov,
          (f16x4*)&embc[(size_t)t * N * H + (size_t)v * H + c0]);
    }
  }
}

// ---------------- fused gates GEMM + LSTM cell (fp16, global_load_lds) ------
// 256 thr = 4 waves (wr x wc = 2x2). Block tile: 128 rows x 128 logical cols
// (jj = gate*32 + wc*16 + lr -> global j = gate*128 + ch0 + ...), so each wave
// holds (i,f,g,o) of the same (row, channel): cell update in-register.
// K: 8 kblocks of 32 fp16 — kb 0..3 stage emb_t[N][128], kb 4..7 stage
// h_{t-1}[N][128] (uniform branch). Double-buffered 2x16KB LDS via
// global_load_lds; granule swizzle slot = q ^ ((row>>1)&3) (2-way, free),
// applied by pre-swizzling the GLOBAL source granule (rule #21).
// h_t written to the compact fp16 oH[N][128] plane (ping-pong, no race).
template<bool FIRST>
__global__ __launch_bounds__(256) void k_gates_cell(const _Float16* __restrict__ embt,
                                                    const _Float16* __restrict__ hcur,
                                                    const _Float16* __restrict__ Bt,
                                                    const float* __restrict__ bih,
                                                    const float* __restrict__ bhh,
                                                    float* __restrict__ cbuf,
                                                    _Float16* __restrict__ oH) {
  __shared__ _Float16 ls[2][8192];   // 2 x 16KB: [A 8KB | B 8KB]
  const int tid = threadIdx.x;
  const int lane = tid & 63, wid = tid >> 6;
  const int wr = wid >> 1, wc = wid & 1;
  const int lr = lane & 15;
  const int g  = lane >> 4;                 // k granule 0..3 (8 fp16 each)

  // bijective XCD-chunk swizzle (m204)
  int xcd = blockIdx.x & 7, loc = blockIdx.x >> 3;
  int wgid = (xcd < GRR ? xcd * (GQQ + 1) : GRR * (GQQ + 1) + (xcd - GRR) * GQQ) + loc;
  const int rb  = (wgid >> 2) * 128;
  const int ch0 = (wgid & 3) * 32;

  f32x4 acc[4][4];
  #pragma unroll
  for (int mi = 0; mi < 4; ++mi)
    #pragma unroll
    for (int ni = 0; ni < 4; ++ni) acc[mi][ni] = (f32x4)0.0f;

  // stage one 16KB k-block tile (async, no data registers)
  auto stage = [&](int buf, int kb) {
    const _Float16* srcA = (kb < 4) ? embt : hcur;   // both [N(P)][128]
    int koA = (kb & 3) * 32;
    int koB = kb * 32;
    _Float16* lb = &ls[buf][0];
    #pragma unroll
    for (int i = 0; i < 2; ++i) {
      int c = i * 256 + tid;               // 16B chunk id 0..511
      int row = c >> 2, slot = c & 3;
      int g3 = slot ^ ((row >> 1) & 3);    // pre-swizzled global granule
      size_t ga = (size_t)(rb + row) * H + koA + g3 * 8;
      gll16(srcA + ga, lb + c * 8);
      int j = (row >> 5) * 128 + ch0 + (row & 31);
      size_t gb = (size_t)j * 256 + koB + g3 * 8;
      gll16(Bt + gb, lb + 4096 + c * 8);
    }
  };

  auto compute = [&](int buf) {
    const _Float16* lb = &ls[buf][0];
    f16x8 bfr[4];
    #pragma unroll
    for (int ni = 0; ni < 4; ++ni) {
      int jj = ni * 32 + wc * 16 + lr;
      bfr[ni] = *(const f16x8*)(lb + 4096 + jj * 32 + (g ^ ((jj >> 1) & 3)) * 8);
    }
    #pragma unroll
    for (int mi = 0; mi < 4; ++mi) {
      int rr = wr * 64 + mi * 16 + lr;
      f16x8 afr = *(const f16x8*)(lb + rr * 32 + (g ^ ((rr >> 1) & 3)) * 8);
      #pragma unroll
      for (int ni = 0; ni < 4; ++ni)
        acc[mi][ni] = __builtin_amdgcn_mfma_f32_16x16x32_f16(afr, bfr[ni], acc[mi][ni], 0, 0, 0);
    }
  };

  const int kbs = FIRST ? 4 : 8;            // t=0: h==0, skip upper K half
  stage(0, 0);
  for (int kb = 0; kb < kbs; ++kb) {
    __syncthreads();                        // buf[kb&1] staged; prev reads done
    if (kb + 1 < kbs) stage((kb + 1) & 1, kb + 1);  // async, hides under MFMAs
    compute(kb & 1);
  }

  int ch = ch0 + wc * 16 + lr;
  float bi_ = bih[ch]       + bhh[ch];
  float bf_ = bih[128 + ch] + bhh[128 + ch];
  float bg_ = bih[256 + ch] + bhh[256 + ch];
  float bo_ = bih[384 + ch] + bhh[384 + ch];
  int orow = (lane >> 4) * 4;
  int rbw = rb + wr * 64;
  #pragma unroll
  for (int mi = 0; mi < 4; ++mi) {
    #pragma unroll
    for (int r = 0; r < 4; ++r) {
      int n = rbw + mi * 16 + orow + r;
      if (n >= N) continue;
      float gi = acc[mi][0][r] + bi_;
      float gf = acc[mi][1][r] + bf_;
      float gg = acc[mi][2][r] + bg_;
      float go = acc[mi][3][r] + bo_;
      float si = 1.f / (1.f + expf(-gi));
      float sf = 1.f / (1.f + expf(-gf));
      float so = 1.f / (1.f + expf(-go));
      float tg = tanhf(gg);
      size_t ci = (size_t)n * H + ch;
      float cn = FIRST ? si * tg : fmaf(sf, cbuf[ci], si * tg);
      cbuf[ci] = cn;
      float hn = so * tanhf(cn);
      oH[ci] = (_Float16)hn;
    }
  }
}

// ---------------- FC (MFMA): out[n][t][:] = h[n] @ W_fc^T + b_fc ----------------
// h fp16 from compact plane [N][128]; Wfc fp16 [32][128]. Wave = 64 rows x 32
// cols (mi=4, ni=2, 4 kblocks -> 32 MFMAs). Block 256 thr = 4 waves = 256 rows.
__global__ __launch_bounds__(256) void k_fc_mfma(const _Float16* __restrict__ Hc,
                                                 const _Float16* __restrict__ w16,
                                                 const float* __restrict__ bfc,
                                                 float* __restrict__ outp, int t) {
  int lane = threadIdx.x & 63, wid = threadIdx.x >> 6;
  int rb = blockIdx.x * 256 + wid * 64;
  int lr = lane & 15, g = lane >> 4;
  f32x4 acc[4][2];
  #pragma unroll
  for (int mi = 0; mi < 4; ++mi) { acc[mi][0] = (f32x4)0.0f; acc[mi][1] = (f32x4)0.0f; }

  #pragma unroll
  for (int kb = 0; kb < 4; ++kb) {
    int ko = kb * 32 + g * 8;
    f16x8 bfr[2];
    #pragma unroll
    for (int ni = 0; ni < 2; ++ni)
      bfr[ni] = *(const f16x8*)&w16[(ni * 16 + lr) * H + ko];
    #pragma unroll
    for (int mi = 0; mi < 4; ++mi) {
      int n = rb + mi * 16 + lr;
      n = n < N ? n : N - 1;               // clamp (pad rows discarded)
      f16x8 afr = *(const f16x8*)&Hc[(size_t)n * H + ko];
      #pragma unroll
      for (int ni = 0; ni < 2; ++ni)
        acc[mi][ni] = __builtin_amdgcn_mfma_f32_16x16x32_f16(afr, bfr[ni], acc[mi][ni], 0, 0, 0);
    }
  }
  int orow = g * 4;
  #pragma unroll
  for (int ni = 0; ni < 2; ++ni) {
    int oc = ni * 16 + lr;
    float bb = bfc[oc];
    #pragma unroll
    for (int mi = 0; mi < 4; ++mi)
      #pragma unroll
      for (int r = 0; r < 4; ++r) {
        int n = rb + mi * 16 + orow + r;
        if (n < N) outp[((size_t)n * T + t) * OUTD + oc] = acc[mi][ni][r] + bb;
      }
  }
}

// ---------------------------------------------------------------------------

extern "C" void kernel_launch(void* const* d_in, const int* in_sizes, int n_in,
                              void* d_out, int out_size, void* d_ws, size_t ws_size,
                              hipStream_t stream) {
  const float* x_seq = (const float*)d_in[0];
  const int*   eidx  = (const int*)d_in[1];
  const int*   erow  = eidx;          // sources
  const int*   ecol  = eidx + E;      // targets
  const float* W_gcn = (const float*)d_in[2];
  const float* b_gcn = (const float*)d_in[3];
  const float* W_ih  = (const float*)d_in[4];
  const float* W_hh  = (const float*)d_in[5];
  const float* b_ih  = (const float*)d_in[6];
  const float* b_hh  = (const float*)d_in[7];
  const float* W_fc  = (const float*)d_in[8];
  const float* b_fc  = (const float*)d_in[9];
  float* outp = (float*)d_out;

  char* base = (char*)d_ws;
  size_t o = 0;
  auto alloc = [&](size_t bytes) -> void* {
    void* p = base + o;
    o += (bytes + 255) & ~(size_t)255;
    return p;
  };
  int*   cnt      = (int*)  alloc((size_t)N * 4);
  int*   cursor   = (int*)  alloc((size_t)N * 4);
  int*   offv     = (int*)  alloc((size_t)(N + 1) * 4);
  int*   csum     = (int*)  alloc((size_t)(NCH + 1) * 4);
  int*   coff     = (int*)  alloc((size_t)(NCH + 1) * 4);
  float* dinv     = (float*)alloc((size_t)N * 4);
  int2*  csr      = (int2*) alloc((size_t)E * 8);
  _Float16* bt    = (_Float16*)alloc((size_t)G * 256 * 2);
  _Float16* bgT   = (_Float16*)alloc((size_t)H * H * 2);
  _Float16* wfc16 = (_Float16*)alloc((size_t)OUTD * H * 2);
  _Float16* xwA   = (_Float16*)alloc((size_t)N * TCA * H * 2);       // 64 MB
  _Float16* xwB   = (_Float16*)alloc((size_t)N * TCB * H * 2);       // 51 MB
  _Float16* emb_all= (_Float16*)alloc((size_t)(T * N + 128) * H * 2); // [T][N][H] + pad
  _Float16* h0    = (_Float16*)alloc((size_t)NP * H * 2);            // compact h, even t
  _Float16* h1    = (_Float16*)alloc((size_t)NP * H * 2);            // odd t
  float* cbuf     = (float*)alloc((size_t)N * H * 4);
  (void)ws_size; (void)in_sizes; (void)n_in; (void)out_size;

  _Float16* HP[2] = {h0, h1};

  // only the small CSR counters need zeroing; h/c state handled by the
  // FIRST-step specialization; pad rows only affect discarded output rows.
  hipMemsetAsync(cnt,    0, (size_t)N * 4, stream);
  hipMemsetAsync(cursor, 0, (size_t)N * 4, stream);

  k_count<<<E / 256, 256, 0, stream>>>(ecol, cnt);
  k_dinv<<<(N + 255) / 256, 256, 0, stream>>>(cnt, dinv);
  k_chunk_sum<<<NCH, SCAN_CH, 0, stream>>>(cnt, csum);
  k_chunk_scan<<<1, 64, 0, stream>>>(csum, coff);
  k_scan_final<<<NCH, SCAN_CH, 0, stream>>>(cnt, coff, offv);
  k_fill<<<E / 256, 256, 0, stream>>>(erow, ecol, dinv, offv, cursor, csr);
  k_wprep_lstm<<<(G * 256) / 256, 256, 0, stream>>>(W_ih, W_hh, bt);
  k_wprep_gcn<<<(H * H) / 256, 256, 0, stream>>>(W_gcn, bgT);
  k_wprep_fc<<<(OUTD * H + 255) / 256, 256, 0, stream>>>(W_fc, wfc16);

  // all 9 GCN GEMMs in one dispatch (no LSTM dependence)
  k_gcn_all<<<dim3(NP / 128, T), 256, 0, stream>>>(x_seq, bgT, xwA, xwB);
  // aggregation in 2 t-chunk passes (per-pass hot set 51-64MB, L3-resident)
  k_agg_chunk<TCA><<<N / 4, 256, 0, stream>>>(xwA, offv, (const long long*)csr,
                                              dinv, b_gcn, emb_all);
  k_agg_chunk<TCB><<<N / 4, 256, 0, stream>>>(xwB, offv, (const long long*)csr,
                                              dinv, b_gcn,
                                              emb_all + (size_t)TCA * N * H);

  int fcblocks = (NP + 255) / 256;        // 196
  for (int t = 0; t < T; ++t) {
    int cur = t & 1, nxt = cur ^ 1;
    const _Float16* embt = emb_all + (size_t)t * N * H;
    if (t == 0)
      k_gates_cell<true><<<GNWG, 256, 0, stream>>>(
          embt, HP[cur], bt, b_ih, b_hh, cbuf, HP[nxt]);
    else
      k_gates_cell<false><<<GNWG, 256, 0, stream>>>(
          embt, HP[cur], bt, b_ih, b_hh, cbuf, HP[nxt]);
    k_fc_mfma<<<fcblocks, 256, 0, stream>>>(HP[nxt], wfc16, b_fc, outp, t);
  }
}

// Round 16
// 1202.966 us; speedup vs baseline: 1.0478x; 1.0433x over previous
//
#include <hip/hip_runtime.h>
#include <cstdint>
#include <cstddef>

// ---------------------------------------------------------------------------
// GCN(1 layer, sym-norm w/ self loops) -> LSTM(1 layer, T=9) -> FC, eval mode
// Round 16: FC phase batched into ONE dispatch (grid 196x9) after the
// recurrence; h stored in per-t planes h_all[t][N][H] (gates writes plane t,
// reads plane t-1 — no ping-pong). Removes 9 launches + tails + gaps from
// the serial chain. agg (at its gather ceiling, 2-chunk), gates, CSR
// unchanged from round 15.
// ---------------------------------------------------------------------------

constexpr int N    = 50000;
constexpr int NP   = 50048;  // padded to 128-row strips (391*128)
constexpr int E    = 1600000;
constexpr int T    = 9;
constexpr int H    = 128;    // F_IN == H == 128
constexpr int G    = 512;    // 4*H (gates i,f,g,o)
constexpr int OUTD = 32;
constexpr int TCA  = 5;      // agg chunk A: t = 0..4
constexpr int TCB  = 4;      // agg chunk B: t = 5..8

constexpr int SCAN_CH = 512;
constexpr int NCH = (N + SCAN_CH - 1) / SCAN_CH;   // 98

// gates grid: 391 row-strips x 4 col-quarters
constexpr int GNWG = (NP / 128) * 4;               // 1564
constexpr int GQQ  = GNWG / 8;                     // 195
constexpr int GRR  = GNWG % 8;                     // 4

typedef __attribute__((ext_vector_type(8))) _Float16 f16x8;
typedef __attribute__((ext_vector_type(4))) float f32x4;
typedef __attribute__((ext_vector_type(4))) _Float16 f16x4;

// async global->LDS, 16B per lane; LDS dest = wave-uniform base + lane*16
__device__ __forceinline__ void gll16(const void* g, void* l) {
  __builtin_amdgcn_global_load_lds(
      (const __attribute__((address_space(1))) void*)g,
      (__attribute__((address_space(3))) void*)l, 16, 0, 0);
}

// ---------------- degree / CSR build ----------------

__global__ void k_count(const int* __restrict__ col, int* __restrict__ cnt) {
  int e = blockIdx.x * 256 + threadIdx.x;
  if (e < E) atomicAdd(&cnt[col[e]], 1);
}

__global__ void k_dinv(const int* __restrict__ cnt, float* __restrict__ dinv) {
  int v = blockIdx.x * 256 + threadIdx.x;
  if (v < N) dinv[v] = rsqrtf((float)cnt[v] + 1.0f);   // +1 self loop
}

__global__ void k_chunk_sum(const int* __restrict__ cnt, int* __restrict__ csum) {
  __shared__ int sp[SCAN_CH / 64];
  int i = blockIdx.x * SCAN_CH + threadIdx.x;
  int v = (i < N) ? cnt[i] : 0;
  for (int off = 32; off > 0; off >>= 1) v += __shfl_down(v, off, 64);
  if ((threadIdx.x & 63) == 0) sp[threadIdx.x >> 6] = v;
  __syncthreads();
  if (threadIdx.x == 0) {
    int s = 0;
    #pragma unroll
    for (int w = 0; w < SCAN_CH / 64; ++w) s += sp[w];
    csum[blockIdx.x] = s;
  }
}

__global__ void k_chunk_scan(const int* __restrict__ csum, int* __restrict__ coff) {
  if (blockIdx.x == 0 && threadIdx.x == 0) {
    int run = 0;
    for (int b = 0; b < NCH; ++b) { coff[b] = run; run += csum[b]; }
    coff[NCH] = run;
  }
}

__global__ void k_scan_final(const int* __restrict__ cnt, const int* __restrict__ coff,
                             int* __restrict__ offv) {
  __shared__ int s[SCAN_CH];
  int tid = threadIdx.x;
  int i = blockIdx.x * SCAN_CH + tid;
  int v = (i < N) ? cnt[i] : 0;
  s[tid] = v;
  __syncthreads();
  for (int st = 1; st < SCAN_CH; st <<= 1) {
    int tv = (tid >= st) ? s[tid - st] : 0;
    __syncthreads();
    s[tid] += tv;
    __syncthreads();
  }
  if (i < N) offv[i] = coff[blockIdx.x] + s[tid] - v;   // exclusive
  if (blockIdx.x == 0 && tid == 0) offv[N] = coff[NCH];
}

// packed CSR entry: one 8B scatter per edge (halves write amplification)
__global__ void k_fill(const int* __restrict__ row, const int* __restrict__ col,
                       const float* __restrict__ dinv, const int* __restrict__ offv,
                       int* __restrict__ cursor, int2* __restrict__ csr) {
  int e = blockIdx.x * 256 + threadIdx.x;
  if (e >= E) return;
  int r = row[e], c = col[e];
  int p = atomicAdd(&cursor[c], 1);
  float nm = dinv[r] * dinv[c];
  csr[offv[c] + p] = make_int2(r, __builtin_bit_cast(int, nm));
}

// ---------------- weight prep (once per call) ----------------
// LSTM: bt[j][k] fp16 (j<512, k<256): k<128 -> W_ih[j][k], else W_hh[j][k-128]
__global__ void k_wprep_lstm(const float* __restrict__ Wih, const float* __restrict__ Whh,
                             _Float16* __restrict__ bt) {
  int idx = blockIdx.x * 256 + threadIdx.x;   // 512*256
  if (idx >= G * 256) return;
  int j = idx >> 8, k = idx & 255;
  float f = (k < H) ? Wih[j * H + k] : Whh[j * H + (k - H)];
  bt[idx] = (_Float16)f;
}

// GCN: bgT[j][k] = W_gcn[k][j]  (128x128) fp16
__global__ void k_wprep_gcn(const float* __restrict__ Wg, _Float16* __restrict__ bgT) {
  int idx = blockIdx.x * 256 + threadIdx.x;   // 128*128
  if (idx >= H * H) return;
  int j = idx >> 7, k = idx & 127;
  bgT[idx] = (_Float16)Wg[k * H + j];
}

// FC: wfc16[j][k] fp16 copy of W_fc (32x128)
__global__ void k_wprep_fc(const float* __restrict__ Wfc, _Float16* __restrict__ w16) {
  int idx = blockIdx.x * 256 + threadIdx.x;   // 32*128
  if (idx < OUTD * H) w16[idx] = (_Float16)Wfc[idx];
}

// ---------------- GCN GEMM (MFMA fp16), ALL timesteps ----------------
// Output into two chunk buffers: xwA [N][5*128] (t=0..4), xwB [N][4*128].
// grid (391, 9); block 256 thr = 4 waves (2x2) -> 128 rows x 128 cols.
__global__ __launch_bounds__(256) void k_gcn_all(const float* __restrict__ Xall,
                                                 const _Float16* __restrict__ BgT,
                                                 _Float16* __restrict__ xwA,
                                                 _Float16* __restrict__ xwB) {
  __shared__ _Float16 lsB[16384];   // [kb][j][g'] 16B granules, 32KB
  int t = blockIdx.y;
  const float* X = Xall + (size_t)t * N * H;
  _Float16* xw;
  int rs;
  if (t < TCA) { xw = xwA + t * H;         rs = TCA * H; }
  else         { xw = xwB + (t - TCA) * H; rs = TCB * H; }
  int tid = threadIdx.x;
  int lane = tid & 63, wid = tid >> 6;
  int wr = wid >> 1, wc = wid & 1;
  int rb = blockIdx.x * 128 + wr * 64;
  int cb = wc * 64;
  int lr = lane & 15;
  int g  = lane >> 4;

  #pragma unroll
  for (int i = 0; i < 8; ++i) {           // stage B: 2048 granules of 16B
    int c = i * 256 + tid;
    int kb = c >> 9, j = (c >> 2) & 127, gg = c & 3;
    f16x8 v = *(const f16x8*)&BgT[j * H + kb * 32 + gg * 8];
    int slot = gg ^ ((j >> 1) & 3);
    *(f16x8*)&lsB[kb * 4096 + j * 32 + slot * 8] = v;
  }
  __syncthreads();

  f32x4 acc[4][4];
  #pragma unroll
  for (int mi = 0; mi < 4; ++mi)
    #pragma unroll
    for (int ni = 0; ni < 4; ++ni) acc[mi][ni] = (f32x4)0.0f;

  #pragma unroll
  for (int kb = 0; kb < 4; ++kb) {
    f16x8 bfr[4];
    #pragma unroll
    for (int ni = 0; ni < 4; ++ni) {
      int j = cb + ni * 16 + lr;
      bfr[ni] = *(const f16x8*)&lsB[kb * 4096 + j * 32 + (g ^ ((j >> 1) & 3)) * 8];
    }
    #pragma unroll
    for (int mi = 0; mi < 4; ++mi) {
      int r = rb + mi * 16 + lr;
      r = r < N ? r : N - 1;                     // clamp (pad rows discarded)
      const float* ap = X + (size_t)r * H + kb * 32 + g * 8;
      float4 a0 = *(const float4*)ap;
      float4 a1 = *(const float4*)(ap + 4);
      f16x8 afr;
      afr[0] = (_Float16)a0.x; afr[1] = (_Float16)a0.y;
      afr[2] = (_Float16)a0.z; afr[3] = (_Float16)a0.w;
      afr[4] = (_Float16)a1.x; afr[5] = (_Float16)a1.y;
      afr[6] = (_Float16)a1.z; afr[7] = (_Float16)a1.w;
      #pragma unroll
      for (int ni = 0; ni < 4; ++ni)
        acc[mi][ni] = __builtin_amdgcn_mfma_f32_16x16x32_f16(afr, bfr[ni], acc[mi][ni], 0, 0, 0);
    }
  }
  int orow = (lane >> 4) * 4;
  #pragma unroll
  for (int mi = 0; mi < 4; ++mi)
    #pragma unroll
    for (int ni = 0; ni < 4; ++ni)
      #pragma unroll
      for (int r = 0; r < 4; ++r) {
        int n = rb + mi * 16 + orow + r;
        if (n < N) xw[(size_t)n * rs + cb + ni * 16 + lr] = (_Float16)acc[mi][ni][r];
      }
}

// ---------------- aggregation, one t-chunk per dispatch ----------------
// Wave per vertex; two 32-lane halves process even/odd edges, 2 edges per
// iteration (2*TC loads in flight). Edge meta read once per pass (NT).
// Source region [s][TC*H] contiguous. At the random-gather fabric ceiling.
template<int TC>
__global__ __launch_bounds__(256) void k_agg_chunk(const _Float16* __restrict__ xw,
                                                   const int* __restrict__ offv,
                                                   const long long* __restrict__ csr,
                                                   const float* __restrict__ dinv,
                                                   const float* __restrict__ bg,
                                                   _Float16* __restrict__ embc) {
  constexpr int RS = TC * H;
  int wid = threadIdx.x >> 6, lane = threadIdx.x & 63;
  int v = blockIdx.x * 4 + wid;          // N % 4 == 0
  int half = lane >> 5, sl = lane & 31;
  int c0 = sl * 4;
  float acc[TC][4];
  #pragma unroll
  for (int t = 0; t < TC; ++t) {
    acc[t][0] = 0.f; acc[t][1] = 0.f; acc[t][2] = 0.f; acc[t][3] = 0.f;
  }
  if (half == 0) {                       // self term once
    float dv = dinv[v];
    float w = dv * dv;
    const _Float16* xp = xw + (size_t)v * RS + c0;
    #pragma unroll
    for (int t = 0; t < TC; ++t) {
      f16x4 xs = *(const f16x4*)(xp + t * H);
      acc[t][0] = (float)xs.x * w; acc[t][1] = (float)xs.y * w;
      acc[t][2] = (float)xs.z * w; acc[t][3] = (float)xs.w * w;
    }
  }
  int e0 = offv[v], e1 = offv[v + 1];
  int e = e0 + half;
  for (; e + 2 < e1; e += 4) {           // 2 edges in flight per half
    long long r0 = __builtin_nontemporal_load(&csr[e]);
    long long r1 = __builtin_nontemporal_load(&csr[e + 2]);
    int s0 = (int)(r0 & 0xffffffffLL);
    int s1 = (int)(r1 & 0xffffffffLL);
    float m0 = __builtin_bit_cast(float, (int)(r0 >> 32));
    float m1 = __builtin_bit_cast(float, (int)(r1 >> 32));
    const _Float16* xp0 = xw + (size_t)s0 * RS + c0;
    const _Float16* xp1 = xw + (size_t)s1 * RS + c0;
    f16x4 xa[TC], xb[TC];
    #pragma unroll
    for (int t = 0; t < TC; ++t) {
      xa[t] = *(const f16x4*)(xp0 + t * H);
      xb[t] = *(const f16x4*)(xp1 + t * H);
    }
    #pragma unroll
    for (int t = 0; t < TC; ++t) {
      acc[t][0] = fmaf((float)xa[t].x, m0, acc[t][0]);
      acc[t][1] = fmaf((float)xa[t].y, m0, acc[t][1]);
      acc[t][2] = fmaf((float)xa[t].z, m0, acc[t][2]);
      acc[t][3] = fmaf((float)xa[t].w, m0, acc[t][3]);
      acc[t][0] = fmaf((float)xb[t].x, m1, acc[t][0]);
      acc[t][1] = fmaf((float)xb[t].y, m1, acc[t][1]);
      acc[t][2] = fmaf((float)xb[t].z, m1, acc[t][2]);
      acc[t][3] = fmaf((float)xb[t].w, m1, acc[t][3]);
    }
  }
  if (e < e1) {                          // tail edge
    long long r0 = __builtin_nontemporal_load(&csr[e]);
    int s0 = (int)(r0 & 0xffffffffLL);
    float m0 = __builtin_bit_cast(float, (int)(r0 >> 32));
    const _Float16* xp0 = xw + (size_t)s0 * RS + c0;
    #pragma unroll
    for (int t = 0; t < TC; ++t) {
      f16x4 x = *(const f16x4*)(xp0 + t * H);
      acc[t][0] = fmaf((float)x.x, m0, acc[t][0]);
      acc[t][1] = fmaf((float)x.y, m0, acc[t][1]);
      acc[t][2] = fmaf((float)x.z, m0, acc[t][2]);
      acc[t][3] = fmaf((float)x.w, m0, acc[t][3]);
    }
  }
  #pragma unroll
  for (int t = 0; t < TC; ++t) {
    acc[t][0] += __shfl_xor(acc[t][0], 32, 64);
    acc[t][1] += __shfl_xor(acc[t][1], 32, 64);
    acc[t][2] += __shfl_xor(acc[t][2], 32, 64);
    acc[t][3] += __shfl_xor(acc[t][3], 32, 64);
  }
  if (half == 0) {
    float4 bb = *(const float4*)&bg[c0];
    #pragma unroll
    for (int t = 0; t < TC; ++t) {
      f16x4 ov;
      ov.x = (_Float16)fmaxf(acc[t][0] + bb.x, 0.f);
      ov.y = (_Float16)fmaxf(acc[t][1] + bb.y, 0.f);
      ov.z = (_Float16)fmaxf(acc[t][2] + bb.z, 0.f);
      ov.w = (_Float16)fmaxf(acc[t][3] + bb.w, 0.f);
      __builtin_nontemporal_store(ov,
          (f16x4*)&embc[(size_t)t * N * H + (size_t)v * H + c0]);
    }
  }
}

// ---------------- fused gates GEMM + LSTM cell (fp16, global_load_lds) ------
// 256 thr = 4 waves (wr x wc = 2x2). Block tile: 128 rows x 128 logical cols
// (jj = gate*32 + wc*16 + lr -> global j = gate*128 + ch0 + ...), so each wave
// holds (i,f,g,o) of the same (row, channel): cell update in-register.
// K: 8 kblocks of 32 fp16 — kb 0..3 stage emb_t[N][128], kb 4..7 stage
// h_{t-1}[N][128] (uniform branch). Double-buffered 2x16KB LDS via
// global_load_lds; granule swizzle slot = q ^ ((row>>1)&3) (2-way, free),
// applied by pre-swizzling the GLOBAL source granule (rule #21).
// h_t written to its own plane h_all[t][N][128] (plane != hcur plane: no race).
template<bool FIRST>
__global__ __launch_bounds__(256) void k_gates_cell(const _Float16* __restrict__ embt,
                                                    const _Float16* __restrict__ hcur,
                                                    const _Float16* __restrict__ Bt,
                                                    const float* __restrict__ bih,
                                                    const float* __restrict__ bhh,
                                                    float* __restrict__ cbuf,
                                                    _Float16* __restrict__ oH) {
  __shared__ _Float16 ls[2][8192];   // 2 x 16KB: [A 8KB | B 8KB]
  const int tid = threadIdx.x;
  const int lane = tid & 63, wid = tid >> 6;
  const int wr = wid >> 1, wc = wid & 1;
  const int lr = lane & 15;
  const int g  = lane >> 4;                 // k granule 0..3 (8 fp16 each)

  // bijective XCD-chunk swizzle (m204)
  int xcd = blockIdx.x & 7, loc = blockIdx.x >> 3;
  int wgid = (xcd < GRR ? xcd * (GQQ + 1) : GRR * (GQQ + 1) + (xcd - GRR) * GQQ) + loc;
  const int rb  = (wgid >> 2) * 128;
  const int ch0 = (wgid & 3) * 32;

  f32x4 acc[4][4];
  #pragma unroll
  for (int mi = 0; mi < 4; ++mi)
    #pragma unroll
    for (int ni = 0; ni < 4; ++ni) acc[mi][ni] = (f32x4)0.0f;

  // stage one 16KB k-block tile (async, no data registers)
  auto stage = [&](int buf, int kb) {
    const _Float16* srcA = (kb < 4) ? embt : hcur;   // both [N(P)][128]
    int koA = (kb & 3) * 32;
    int koB = kb * 32;
    _Float16* lb = &ls[buf][0];
    #pragma unroll
    for (int i = 0; i < 2; ++i) {
      int c = i * 256 + tid;               // 16B chunk id 0..511
      int row = c >> 2, slot = c & 3;
      int g3 = slot ^ ((row >> 1) & 3);    // pre-swizzled global granule
      size_t ga = (size_t)(rb + row) * H + koA + g3 * 8;
      gll16(srcA + ga, lb + c * 8);
      int j = (row >> 5) * 128 + ch0 + (row & 31);
      size_t gb = (size_t)j * 256 + koB + g3 * 8;
      gll16(Bt + gb, lb + 4096 + c * 8);
    }
  };

  auto compute = [&](int buf) {
    const _Float16* lb = &ls[buf][0];
    f16x8 bfr[4];
    #pragma unroll
    for (int ni = 0; ni < 4; ++ni) {
      int jj = ni * 32 + wc * 16 + lr;
      bfr[ni] = *(const f16x8*)(lb + 4096 + jj * 32 + (g ^ ((jj >> 1) & 3)) * 8);
    }
    #pragma unroll
    for (int mi = 0; mi < 4; ++mi) {
      int rr = wr * 64 + mi * 16 + lr;
      f16x8 afr = *(const f16x8*)(lb + rr * 32 + (g ^ ((rr >> 1) & 3)) * 8);
      #pragma unroll
      for (int ni = 0; ni < 4; ++ni)
        acc[mi][ni] = __builtin_amdgcn_mfma_f32_16x16x32_f16(afr, bfr[ni], acc[mi][ni], 0, 0, 0);
    }
  };

  const int kbs = FIRST ? 4 : 8;            // t=0: h==0, skip upper K half
  stage(0, 0);
  for (int kb = 0; kb < kbs; ++kb) {
    __syncthreads();                        // buf[kb&1] staged; prev reads done
    if (kb + 1 < kbs) stage((kb + 1) & 1, kb + 1);  // async, hides under MFMAs
    compute(kb & 1);
  }

  int ch = ch0 + wc * 16 + lr;
  float bi_ = bih[ch]       + bhh[ch];
  float bf_ = bih[128 + ch] + bhh[128 + ch];
  float bg_ = bih[256 + ch] + bhh[256 + ch];
  float bo_ = bih[384 + ch] + bhh[384 + ch];
  int orow = (lane >> 4) * 4;
  int rbw = rb + wr * 64;
  #pragma unroll
  for (int mi = 0; mi < 4; ++mi) {
    #pragma unroll
    for (int r = 0; r < 4; ++r) {
      int n = rbw + mi * 16 + orow + r;
      if (n >= N) continue;
      float gi = acc[mi][0][r] + bi_;
      float gf = acc[mi][1][r] + bf_;
      float gg = acc[mi][2][r] + bg_;
      float go = acc[mi][3][r] + bo_;
      float si = 1.f / (1.f + expf(-gi));
      float sf = 1.f / (1.f + expf(-gf));
      float so = 1.f / (1.f + expf(-go));
      float tg = tanhf(gg);
      size_t ci = (size_t)n * H + ch;
      float cn = FIRST ? si * tg : fmaf(sf, cbuf[ci], si * tg);
      cbuf[ci] = cn;
      float hn = so * tanhf(cn);
      oH[ci] = (_Float16)hn;
    }
  }
}

// ---------------- FC (MFMA), ALL timesteps in one dispatch ----------------
// grid (196, 9). h fp16 from h_all plane t; Wfc fp16 [32][128]. Wave = 64
// rows x 32 cols (mi=4, ni=2, 4 kblocks -> 32 MFMAs). 4 waves = 256 rows.
__global__ __launch_bounds__(256) void k_fc_all(const _Float16* __restrict__ h_all,
                                                const _Float16* __restrict__ w16,
                                                const float* __restrict__ bfc,
                                                float* __restrict__ outp) {
  int t = blockIdx.y;
  const _Float16* Hc = h_all + (size_t)t * N * H;
  int lane = threadIdx.x & 63, wid = threadIdx.x >> 6;
  int rb = blockIdx.x * 256 + wid * 64;
  int lr = lane & 15, g = lane >> 4;
  f32x4 acc[4][2];
  #pragma unroll
  for (int mi = 0; mi < 4; ++mi) { acc[mi][0] = (f32x4)0.0f; acc[mi][1] = (f32x4)0.0f; }

  #pragma unroll
  for (int kb = 0; kb < 4; ++kb) {
    int ko = kb * 32 + g * 8;
    f16x8 bfr[2];
    #pragma unroll
    for (int ni = 0; ni < 2; ++ni)
      bfr[ni] = *(const f16x8*)&w16[(ni * 16 + lr) * H + ko];
    #pragma unroll
    for (int mi = 0; mi < 4; ++mi) {
      int n = rb + mi * 16 + lr;
      n = n < N ? n : N - 1;               // clamp (pad rows discarded)
      f16x8 afr = *(const f16x8*)&Hc[(size_t)n * H + ko];
      #pragma unroll
      for (int ni = 0; ni < 2; ++ni)
        acc[mi][ni] = __builtin_amdgcn_mfma_f32_16x16x32_f16(afr, bfr[ni], acc[mi][ni], 0, 0, 0);
    }
  }
  int orow = g * 4;
  #pragma unroll
  for (int ni = 0; ni < 2; ++ni) {
    int oc = ni * 16 + lr;
    float bb = bfc[oc];
    #pragma unroll
    for (int mi = 0; mi < 4; ++mi)
      #pragma unroll
      for (int r = 0; r < 4; ++r) {
        int n = rb + mi * 16 + orow + r;
        if (n < N) outp[((size_t)n * T + t) * OUTD + oc] = acc[mi][ni][r] + bb;
      }
  }
}

// ---------------------------------------------------------------------------

extern "C" void kernel_launch(void* const* d_in, const int* in_sizes, int n_in,
                              void* d_out, int out_size, void* d_ws, size_t ws_size,
                              hipStream_t stream) {
  const float* x_seq = (const float*)d_in[0];
  const int*   eidx  = (const int*)d_in[1];
  const int*   erow  = eidx;          // sources
  const int*   ecol  = eidx + E;      // targets
  const float* W_gcn = (const float*)d_in[2];
  const float* b_gcn = (const float*)d_in[3];
  const float* W_ih  = (const float*)d_in[4];
  const float* W_hh  = (const float*)d_in[5];
  const float* b_ih  = (const float*)d_in[6];
  const float* b_hh  = (const float*)d_in[7];
  const float* W_fc  = (const float*)d_in[8];
  const float* b_fc  = (const float*)d_in[9];
  float* outp = (float*)d_out;

  char* base = (char*)d_ws;
  size_t o = 0;
  auto alloc = [&](size_t bytes) -> void* {
    void* p = base + o;
    o += (bytes + 255) & ~(size_t)255;
    return p;
  };
  int*   cnt      = (int*)  alloc((size_t)N * 4);
  int*   cursor   = (int*)  alloc((size_t)N * 4);
  int*   offv     = (int*)  alloc((size_t)(N + 1) * 4);
  int*   csum     = (int*)  alloc((size_t)(NCH + 1) * 4);
  int*   coff     = (int*)  alloc((size_t)(NCH + 1) * 4);
  float* dinv     = (float*)alloc((size_t)N * 4);
  int2*  csr      = (int2*) alloc((size_t)E * 8);
  _Float16* bt    = (_Float16*)alloc((size_t)G * 256 * 2);
  _Float16* bgT   = (_Float16*)alloc((size_t)H * H * 2);
  _Float16* wfc16 = (_Float16*)alloc((size_t)OUTD * H * 2);
  _Float16* xwA   = (_Float16*)alloc((size_t)N * TCA * H * 2);       // 64 MB
  _Float16* xwB   = (_Float16*)alloc((size_t)N * TCB * H * 2);       // 51 MB
  _Float16* emb_all= (_Float16*)alloc((size_t)(T * N + 128) * H * 2); // [T][N][H] + pad
  _Float16* h_all = (_Float16*)alloc((size_t)(T * N + 128) * H * 2);  // [T][N][H] + pad
  float* cbuf     = (float*)alloc((size_t)N * H * 4);
  (void)ws_size; (void)in_sizes; (void)n_in; (void)out_size;

  // only the small CSR counters need zeroing; h/c state handled by the
  // FIRST-step specialization; pad rows only affect discarded output rows.
  hipMemsetAsync(cnt,    0, (size_t)N * 4, stream);
  hipMemsetAsync(cursor, 0, (size_t)N * 4, stream);

  k_count<<<E / 256, 256, 0, stream>>>(ecol, cnt);
  k_dinv<<<(N + 255) / 256, 256, 0, stream>>>(cnt, dinv);
  k_chunk_sum<<<NCH, SCAN_CH, 0, stream>>>(cnt, csum);
  k_chunk_scan<<<1, 64, 0, stream>>>(csum, coff);
  k_scan_final<<<NCH, SCAN_CH, 0, stream>>>(cnt, coff, offv);
  k_fill<<<E / 256, 256, 0, stream>>>(erow, ecol, dinv, offv, cursor, csr);
  k_wprep_lstm<<<(G * 256) / 256, 256, 0, stream>>>(W_ih, W_hh, bt);
  k_wprep_gcn<<<(H * H) / 256, 256, 0, stream>>>(W_gcn, bgT);
  k_wprep_fc<<<(OUTD * H + 255) / 256, 256, 0, stream>>>(W_fc, wfc16);

  // all 9 GCN GEMMs in one dispatch (no LSTM dependence)
  k_gcn_all<<<dim3(NP / 128, T), 256, 0, stream>>>(x_seq, bgT, xwA, xwB);
  // aggregation in 2 t-chunk passes (at the random-gather ceiling)
  k_agg_chunk<TCA><<<N / 4, 256, 0, stream>>>(xwA, offv, (const long long*)csr,
                                              dinv, b_gcn, emb_all);
  k_agg_chunk<TCB><<<N / 4, 256, 0, stream>>>(xwB, offv, (const long long*)csr,
                                              dinv, b_gcn,
                                              emb_all + (size_t)TCA * N * H);

  // LSTM recurrence: gates+cell only (h_t -> plane t of h_all)
  for (int t = 0; t < T; ++t) {
    const _Float16* embt = emb_all + (size_t)t * N * H;
    const _Float16* hcur = (t == 0) ? h_all : h_all + (size_t)(t - 1) * N * H;
    _Float16* oH = h_all + (size_t)t * N * H;
    if (t == 0)
      k_gates_cell<true><<<GNWG, 256, 0, stream>>>(
          embt, hcur, bt, b_ih, b_hh, cbuf, oH);
    else
      k_gates_cell<false><<<GNWG, 256, 0, stream>>>(
          embt, hcur, bt, b_ih, b_hh, cbuf, oH);
  }
  // all 9 FC GEMMs in one dispatch
  k_fc_all<<<dim3((NP + 255) / 256, T), 256, 0, stream>>>(h_all, wfc16, b_fc, outp);
}

// Round 17
// 1186.774 us; speedup vs baseline: 1.0621x; 1.0136x over previous
//
#include <hip/hip_runtime.h>
#include <cstdint>
#include <cstddef>

// ---------------------------------------------------------------------------
// GCN(1 layer, sym-norm w/ self loops) -> LSTM(1 layer, T=9) -> FC, eval mode
// Round 17: gates pipeline deepened — 3x16KB LDS buffers, 2-deep prefetch,
// counted s_waitcnt vmcnt(4) + raw s_barrier (loads stay in flight ACROSS the
// barrier; no vmcnt(0) drain per k-block). Stage = exactly 4 global_load_lds
// per thread -> vmcnt granularity 4. Everything else unchanged from round 16.
// ---------------------------------------------------------------------------

constexpr int N    = 50000;
constexpr int NP   = 50048;  // padded to 128-row strips (391*128)
constexpr int E    = 1600000;
constexpr int T    = 9;
constexpr int H    = 128;    // F_IN == H == 128
constexpr int G    = 512;    // 4*H (gates i,f,g,o)
constexpr int OUTD = 32;
constexpr int TCA  = 5;      // agg chunk A: t = 0..4
constexpr int TCB  = 4;      // agg chunk B: t = 5..8

constexpr int SCAN_CH = 512;
constexpr int NCH = (N + SCAN_CH - 1) / SCAN_CH;   // 98

// gates grid: 391 row-strips x 4 col-quarters
constexpr int GNWG = (NP / 128) * 4;               // 1564
constexpr int GQQ  = GNWG / 8;                     // 195
constexpr int GRR  = GNWG % 8;                     // 4

typedef __attribute__((ext_vector_type(8))) _Float16 f16x8;
typedef __attribute__((ext_vector_type(4))) float f32x4;
typedef __attribute__((ext_vector_type(4))) _Float16 f16x4;

// async global->LDS, 16B per lane; LDS dest = wave-uniform base + lane*16
__device__ __forceinline__ void gll16(const void* g, void* l) {
  __builtin_amdgcn_global_load_lds(
      (const __attribute__((address_space(1))) void*)g,
      (__attribute__((address_space(3))) void*)l, 16, 0, 0);
}

// ---------------- degree / CSR build ----------------

__global__ void k_count(const int* __restrict__ col, int* __restrict__ cnt) {
  int e = blockIdx.x * 256 + threadIdx.x;
  if (e < E) atomicAdd(&cnt[col[e]], 1);
}

__global__ void k_dinv(const int* __restrict__ cnt, float* __restrict__ dinv) {
  int v = blockIdx.x * 256 + threadIdx.x;
  if (v < N) dinv[v] = rsqrtf((float)cnt[v] + 1.0f);   // +1 self loop
}

__global__ void k_chunk_sum(const int* __restrict__ cnt, int* __restrict__ csum) {
  __shared__ int sp[SCAN_CH / 64];
  int i = blockIdx.x * SCAN_CH + threadIdx.x;
  int v = (i < N) ? cnt[i] : 0;
  for (int off = 32; off > 0; off >>= 1) v += __shfl_down(v, off, 64);
  if ((threadIdx.x & 63) == 0) sp[threadIdx.x >> 6] = v;
  __syncthreads();
  if (threadIdx.x == 0) {
    int s = 0;
    #pragma unroll
    for (int w = 0; w < SCAN_CH / 64; ++w) s += sp[w];
    csum[blockIdx.x] = s;
  }
}

__global__ void k_chunk_scan(const int* __restrict__ csum, int* __restrict__ coff) {
  if (blockIdx.x == 0 && threadIdx.x == 0) {
    int run = 0;
    for (int b = 0; b < NCH; ++b) { coff[b] = run; run += csum[b]; }
    coff[NCH] = run;
  }
}

__global__ void k_scan_final(const int* __restrict__ cnt, const int* __restrict__ coff,
                             int* __restrict__ offv) {
  __shared__ int s[SCAN_CH];
  int tid = threadIdx.x;
  int i = blockIdx.x * SCAN_CH + tid;
  int v = (i < N) ? cnt[i] : 0;
  s[tid] = v;
  __syncthreads();
  for (int st = 1; st < SCAN_CH; st <<= 1) {
    int tv = (tid >= st) ? s[tid - st] : 0;
    __syncthreads();
    s[tid] += tv;
    __syncthreads();
  }
  if (i < N) offv[i] = coff[blockIdx.x] + s[tid] - v;   // exclusive
  if (blockIdx.x == 0 && tid == 0) offv[N] = coff[NCH];
}

// packed CSR entry: one 8B scatter per edge (halves write amplification)
__global__ void k_fill(const int* __restrict__ row, const int* __restrict__ col,
                       const float* __restrict__ dinv, const int* __restrict__ offv,
                       int* __restrict__ cursor, int2* __restrict__ csr) {
  int e = blockIdx.x * 256 + threadIdx.x;
  if (e >= E) return;
  int r = row[e], c = col[e];
  int p = atomicAdd(&cursor[c], 1);
  float nm = dinv[r] * dinv[c];
  csr[offv[c] + p] = make_int2(r, __builtin_bit_cast(int, nm));
}

// ---------------- weight prep (once per call) ----------------
// LSTM: bt[j][k] fp16 (j<512, k<256): k<128 -> W_ih[j][k], else W_hh[j][k-128]
__global__ void k_wprep_lstm(const float* __restrict__ Wih, const float* __restrict__ Whh,
                             _Float16* __restrict__ bt) {
  int idx = blockIdx.x * 256 + threadIdx.x;   // 512*256
  if (idx >= G * 256) return;
  int j = idx >> 8, k = idx & 255;
  float f = (k < H) ? Wih[j * H + k] : Whh[j * H + (k - H)];
  bt[idx] = (_Float16)f;
}

// GCN: bgT[j][k] = W_gcn[k][j]  (128x128) fp16
__global__ void k_wprep_gcn(const float* __restrict__ Wg, _Float16* __restrict__ bgT) {
  int idx = blockIdx.x * 256 + threadIdx.x;   // 128*128
  if (idx >= H * H) return;
  int j = idx >> 7, k = idx & 127;
  bgT[idx] = (_Float16)Wg[k * H + j];
}

// FC: wfc16[j][k] fp16 copy of W_fc (32x128)
__global__ void k_wprep_fc(const float* __restrict__ Wfc, _Float16* __restrict__ w16) {
  int idx = blockIdx.x * 256 + threadIdx.x;   // 32*128
  if (idx < OUTD * H) w16[idx] = (_Float16)Wfc[idx];
}

// ---------------- GCN GEMM (MFMA fp16), ALL timesteps ----------------
// Output into two chunk buffers: xwA [N][5*128] (t=0..4), xwB [N][4*128].
// grid (391, 9); block 256 thr = 4 waves (2x2) -> 128 rows x 128 cols.
__global__ __launch_bounds__(256) void k_gcn_all(const float* __restrict__ Xall,
                                                 const _Float16* __restrict__ BgT,
                                                 _Float16* __restrict__ xwA,
                                                 _Float16* __restrict__ xwB) {
  __shared__ _Float16 lsB[16384];   // [kb][j][g'] 16B granules, 32KB
  int t = blockIdx.y;
  const float* X = Xall + (size_t)t * N * H;
  _Float16* xw;
  int rs;
  if (t < TCA) { xw = xwA + t * H;         rs = TCA * H; }
  else         { xw = xwB + (t - TCA) * H; rs = TCB * H; }
  int tid = threadIdx.x;
  int lane = tid & 63, wid = tid >> 6;
  int wr = wid >> 1, wc = wid & 1;
  int rb = blockIdx.x * 128 + wr * 64;
  int cb = wc * 64;
  int lr = lane & 15;
  int g  = lane >> 4;

  #pragma unroll
  for (int i = 0; i < 8; ++i) {           // stage B: 2048 granules of 16B
    int c = i * 256 + tid;
    int kb = c >> 9, j = (c >> 2) & 127, gg = c & 3;
    f16x8 v = *(const f16x8*)&BgT[j * H + kb * 32 + gg * 8];
    int slot = gg ^ ((j >> 1) & 3);
    *(f16x8*)&lsB[kb * 4096 + j * 32 + slot * 8] = v;
  }
  __syncthreads();

  f32x4 acc[4][4];
  #pragma unroll
  for (int mi = 0; mi < 4; ++mi)
    #pragma unroll
    for (int ni = 0; ni < 4; ++ni) acc[mi][ni] = (f32x4)0.0f;

  #pragma unroll
  for (int kb = 0; kb < 4; ++kb) {
    f16x8 bfr[4];
    #pragma unroll
    for (int ni = 0; ni < 4; ++ni) {
      int j = cb + ni * 16 + lr;
      bfr[ni] = *(const f16x8*)&lsB[kb * 4096 + j * 32 + (g ^ ((j >> 1) & 3)) * 8];
    }
    #pragma unroll
    for (int mi = 0; mi < 4; ++mi) {
      int r = rb + mi * 16 + lr;
      r = r < N ? r : N - 1;                     // clamp (pad rows discarded)
      const float* ap = X + (size_t)r * H + kb * 32 + g * 8;
      float4 a0 = *(const float4*)ap;
      float4 a1 = *(const float4*)(ap + 4);
      f16x8 afr;
      afr[0] = (_Float16)a0.x; afr[1] = (_Float16)a0.y;
      afr[2] = (_Float16)a0.z; afr[3] = (_Float16)a0.w;
      afr[4] = (_Float16)a1.x; afr[5] = (_Float16)a1.y;
      afr[6] = (_Float16)a1.z; afr[7] = (_Float16)a1.w;
      #pragma unroll
      for (int ni = 0; ni < 4; ++ni)
        acc[mi][ni] = __builtin_amdgcn_mfma_f32_16x16x32_f16(afr, bfr[ni], acc[mi][ni], 0, 0, 0);
    }
  }
  int orow = (lane >> 4) * 4;
  #pragma unroll
  for (int mi = 0; mi < 4; ++mi)
    #pragma unroll
    for (int ni = 0; ni < 4; ++ni)
      #pragma unroll
      for (int r = 0; r < 4; ++r) {
        int n = rb + mi * 16 + orow + r;
        if (n < N) xw[(size_t)n * rs + cb + ni * 16 + lr] = (_Float16)acc[mi][ni][r];
      }
}

// ---------------- aggregation, one t-chunk per dispatch ----------------
// Wave per vertex; two 32-lane halves process even/odd edges, 2 edges per
// iteration (2*TC loads in flight). Edge meta read once per pass (NT).
// Source region [s][TC*H] contiguous. At the random-gather fabric ceiling.
template<int TC>
__global__ __launch_bounds__(256) void k_agg_chunk(const _Float16* __restrict__ xw,
                                                   const int* __restrict__ offv,
                                                   const long long* __restrict__ csr,
                                                   const float* __restrict__ dinv,
                                                   const float* __restrict__ bg,
                                                   _Float16* __restrict__ embc) {
  constexpr int RS = TC * H;
  int wid = threadIdx.x >> 6, lane = threadIdx.x & 63;
  int v = blockIdx.x * 4 + wid;          // N % 4 == 0
  int half = lane >> 5, sl = lane & 31;
  int c0 = sl * 4;
  float acc[TC][4];
  #pragma unroll
  for (int t = 0; t < TC; ++t) {
    acc[t][0] = 0.f; acc[t][1] = 0.f; acc[t][2] = 0.f; acc[t][3] = 0.f;
  }
  if (half == 0) {                       // self term once
    float dv = dinv[v];
    float w = dv * dv;
    const _Float16* xp = xw + (size_t)v * RS + c0;
    #pragma unroll
    for (int t = 0; t < TC; ++t) {
      f16x4 xs = *(const f16x4*)(xp + t * H);
      acc[t][0] = (float)xs.x * w; acc[t][1] = (float)xs.y * w;
      acc[t][2] = (float)xs.z * w; acc[t][3] = (float)xs.w * w;
    }
  }
  int e0 = offv[v], e1 = offv[v + 1];
  int e = e0 + half;
  for (; e + 2 < e1; e += 4) {           // 2 edges in flight per half
    long long r0 = __builtin_nontemporal_load(&csr[e]);
    long long r1 = __builtin_nontemporal_load(&csr[e + 2]);
    int s0 = (int)(r0 & 0xffffffffLL);
    int s1 = (int)(r1 & 0xffffffffLL);
    float m0 = __builtin_bit_cast(float, (int)(r0 >> 32));
    float m1 = __builtin_bit_cast(float, (int)(r1 >> 32));
    const _Float16* xp0 = xw + (size_t)s0 * RS + c0;
    const _Float16* xp1 = xw + (size_t)s1 * RS + c0;
    f16x4 xa[TC], xb[TC];
    #pragma unroll
    for (int t = 0; t < TC; ++t) {
      xa[t] = *(const f16x4*)(xp0 + t * H);
      xb[t] = *(const f16x4*)(xp1 + t * H);
    }
    #pragma unroll
    for (int t = 0; t < TC; ++t) {
      acc[t][0] = fmaf((float)xa[t].x, m0, acc[t][0]);
      acc[t][1] = fmaf((float)xa[t].y, m0, acc[t][1]);
      acc[t][2] = fmaf((float)xa[t].z, m0, acc[t][2]);
      acc[t][3] = fmaf((float)xa[t].w, m0, acc[t][3]);
      acc[t][0] = fmaf((float)xb[t].x, m1, acc[t][0]);
      acc[t][1] = fmaf((float)xb[t].y, m1, acc[t][1]);
      acc[t][2] = fmaf((float)xb[t].z, m1, acc[t][2]);
      acc[t][3] = fmaf((float)xb[t].w, m1, acc[t][3]);
    }
  }
  if (e < e1) {                          // tail edge
    long long r0 = __builtin_nontemporal_load(&csr[e]);
    int s0 = (int)(r0 & 0xffffffffLL);
    float m0 = __builtin_bit_cast(float, (int)(r0 >> 32));
    const _Float16* xp0 = xw + (size_t)s0 * RS + c0;
    #pragma unroll
    for (int t = 0; t < TC; ++t) {
      f16x4 x = *(const f16x4*)(xp0 + t * H);
      acc[t][0] = fmaf((float)x.x, m0, acc[t][0]);
      acc[t][1] = fmaf((float)x.y, m0, acc[t][1]);
      acc[t][2] = fmaf((float)x.z, m0, acc[t][2]);
      acc[t][3] = fmaf((float)x.w, m0, acc[t][3]);
    }
  }
  #pragma unroll
  for (int t = 0; t < TC; ++t) {
    acc[t][0] += __shfl_xor(acc[t][0], 32, 64);
    acc[t][1] += __shfl_xor(acc[t][1], 32, 64);
    acc[t][2] += __shfl_xor(acc[t][2], 32, 64);
    acc[t][3] += __shfl_xor(acc[t][3], 32, 64);
  }
  if (half == 0) {
    float4 bb = *(const float4*)&bg[c0];
    #pragma unroll
    for (int t = 0; t < TC; ++t) {
      f16x4 ov;
      ov.x = (_Float16)fmaxf(acc[t][0] + bb.x, 0.f);
      ov.y = (_Float16)fmaxf(acc[t][1] + bb.y, 0.f);
      ov.z = (_Float16)fmaxf(acc[t][2] + bb.z, 0.f);
      ov.w = (_Float16)fmaxf(acc[t][3] + bb.w, 0.f);
      __builtin_nontemporal_store(ov,
          (f16x4*)&embc[(size_t)t * N * H + (size_t)v * H + c0]);
    }
  }
}

// ---------------- fused gates GEMM + LSTM cell (fp16, deep pipeline) --------
// 256 thr = 4 waves (wr x wc = 2x2). Block tile: 128 rows x 128 logical cols
// (jj = gate*32 + wc*16 + lr -> global j = gate*128 + ch0 + ...), so each wave
// holds (i,f,g,o) of the same (row, channel): cell update in-register.
// K: 8 kblocks of 32 fp16 — kb 0..3 stage emb_t, kb 4..7 stage h_{t-1}.
// 3 x 16KB LDS buffers, 2-deep prefetch: per k-block
//   s_waitcnt vmcnt(4)  (stage kb landed; NEXT stage's 4 loads stay in flight)
//   raw s_barrier; issue stage(kb+2); compute(kb).
// stage() = exactly 4 global_load_lds per thread -> vmcnt granularity 4.
// Overwrite safety: stage(kb+2) target's last reader was compute(kb-1),
// separated by the previous barrier. Granule swizzle unchanged (rule #21).
template<bool FIRST>
__global__ __launch_bounds__(256) void k_gates_cell(const _Float16* __restrict__ embt,
                                                    const _Float16* __restrict__ hcur,
                                                    const _Float16* __restrict__ Bt,
                                                    const float* __restrict__ bih,
                                                    const float* __restrict__ bhh,
                                                    float* __restrict__ cbuf,
                                                    _Float16* __restrict__ oH) {
  __shared__ _Float16 ls[3][8192];   // 3 x 16KB: [A 8KB | B 8KB]
  const int tid = threadIdx.x;
  const int lane = tid & 63, wid = tid >> 6;
  const int wr = wid >> 1, wc = wid & 1;
  const int lr = lane & 15;
  const int g  = lane >> 4;                 // k granule 0..3 (8 fp16 each)

  // bijective XCD-chunk swizzle (m204)
  int xcd = blockIdx.x & 7, loc = blockIdx.x >> 3;
  int wgid = (xcd < GRR ? xcd * (GQQ + 1) : GRR * (GQQ + 1) + (xcd - GRR) * GQQ) + loc;
  const int rb  = (wgid >> 2) * 128;
  const int ch0 = (wgid & 3) * 32;

  f32x4 acc[4][4];
  #pragma unroll
  for (int mi = 0; mi < 4; ++mi)
    #pragma unroll
    for (int ni = 0; ni < 4; ++ni) acc[mi][ni] = (f32x4)0.0f;

  // stage one 16KB k-block tile: EXACTLY 4 global_load_lds per thread
  auto stage = [&](int buf, int kb) {
    const _Float16* srcA = (kb < 4) ? embt : hcur;   // both [N(P)][128]
    int koA = (kb & 3) * 32;
    int koB = kb * 32;
    _Float16* lb = &ls[buf][0];
    #pragma unroll
    for (int i = 0; i < 2; ++i) {
      int c = i * 256 + tid;               // 16B chunk id 0..511
      int row = c >> 2, slot = c & 3;
      int g3 = slot ^ ((row >> 1) & 3);    // pre-swizzled global granule
      size_t ga = (size_t)(rb + row) * H + koA + g3 * 8;
      gll16(srcA + ga, lb + c * 8);
      int j = (row >> 5) * 128 + ch0 + (row & 31);
      size_t gb = (size_t)j * 256 + koB + g3 * 8;
      gll16(Bt + gb, lb + 4096 + c * 8);
    }
  };

  auto compute = [&](int buf) {
    const _Float16* lb = &ls[buf][0];
    f16x8 bfr[4];
    #pragma unroll
    for (int ni = 0; ni < 4; ++ni) {
      int jj = ni * 32 + wc * 16 + lr;
      bfr[ni] = *(const f16x8*)(lb + 4096 + jj * 32 + (g ^ ((jj >> 1) & 3)) * 8);
    }
    #pragma unroll
    for (int mi = 0; mi < 4; ++mi) {
      int rr = wr * 64 + mi * 16 + lr;
      f16x8 afr = *(const f16x8*)(lb + rr * 32 + (g ^ ((rr >> 1) & 3)) * 8);
      #pragma unroll
      for (int ni = 0; ni < 4; ++ni)
        acc[mi][ni] = __builtin_amdgcn_mfma_f32_16x16x32_f16(afr, bfr[ni], acc[mi][ni], 0, 0, 0);
    }
  };

  const int kbs = FIRST ? 4 : 8;            // t=0: h==0, skip upper K half
  stage(0, 0);
  stage(1, 1);
  for (int kb = 0; kb < kbs; ++kb) {
    if (kb + 1 < kbs) asm volatile("s_waitcnt vmcnt(4)" ::: "memory");
    else              asm volatile("s_waitcnt vmcnt(0)" ::: "memory");
    __builtin_amdgcn_s_barrier();
    asm volatile("" ::: "memory");          // no ds_read hoisting above barrier
    if (kb + 2 < kbs) stage((kb + 2) % 3, kb + 2);
    compute(kb % 3);
  }

  int ch = ch0 + wc * 16 + lr;
  float bi_ = bih[ch]       + bhh[ch];
  float bf_ = bih[128 + ch] + bhh[128 + ch];
  float bg_ = bih[256 + ch] + bhh[256 + ch];
  float bo_ = bih[384 + ch] + bhh[384 + ch];
  int orow = (lane >> 4) * 4;
  int rbw = rb + wr * 64;
  #pragma unroll
  for (int mi = 0; mi < 4; ++mi) {
    #pragma unroll
    for (int r = 0; r < 4; ++r) {
      int n = rbw + mi * 16 + orow + r;
      if (n >= N) continue;
      float gi = acc[mi][0][r] + bi_;
      float gf = acc[mi][1][r] + bf_;
      float gg = acc[mi][2][r] + bg_;
      float go = acc[mi][3][r] + bo_;
      float si = 1.f / (1.f + expf(-gi));
      float sf = 1.f / (1.f + expf(-gf));
      float so = 1.f / (1.f + expf(-go));
      float tg = tanhf(gg);
      size_t ci = (size_t)n * H + ch;
      float cn = FIRST ? si * tg : fmaf(sf, cbuf[ci], si * tg);
      cbuf[ci] = cn;
      float hn = so * tanhf(cn);
      oH[ci] = (_Float16)hn;
    }
  }
}

// ---------------- FC (MFMA), ALL timesteps in one dispatch ----------------
// grid (196, 9). h fp16 from h_all plane t; Wfc fp16 [32][128]. Wave = 64
// rows x 32 cols (mi=4, ni=2, 4 kblocks -> 32 MFMAs). 4 waves = 256 rows.
__global__ __launch_bounds__(256) void k_fc_all(const _Float16* __restrict__ h_all,
                                                const _Float16* __restrict__ w16,
                                                const float* __restrict__ bfc,
                                                float* __restrict__ outp) {
  int t = blockIdx.y;
  const _Float16* Hc = h_all + (size_t)t * N * H;
  int lane = threadIdx.x & 63, wid = threadIdx.x >> 6;
  int rb = blockIdx.x * 256 + wid * 64;
  int lr = lane & 15, g = lane >> 4;
  f32x4 acc[4][2];
  #pragma unroll
  for (int mi = 0; mi < 4; ++mi) { acc[mi][0] = (f32x4)0.0f; acc[mi][1] = (f32x4)0.0f; }

  #pragma unroll
  for (int kb = 0; kb < 4; ++kb) {
    int ko = kb * 32 + g * 8;
    f16x8 bfr[2];
    #pragma unroll
    for (int ni = 0; ni < 2; ++ni)
      bfr[ni] = *(const f16x8*)&w16[(ni * 16 + lr) * H + ko];
    #pragma unroll
    for (int mi = 0; mi < 4; ++mi) {
      int n = rb + mi * 16 + lr;
      n = n < N ? n : N - 1;               // clamp (pad rows discarded)
      f16x8 afr = *(const f16x8*)&Hc[(size_t)n * H + ko];
      #pragma unroll
      for (int ni = 0; ni < 2; ++ni)
        acc[mi][ni] = __builtin_amdgcn_mfma_f32_16x16x32_f16(afr, bfr[ni], acc[mi][ni], 0, 0, 0);
    }
  }
  int orow = g * 4;
  #pragma unroll
  for (int ni = 0; ni < 2; ++ni) {
    int oc = ni * 16 + lr;
    float bb = bfc[oc];
    #pragma unroll
    for (int mi = 0; mi < 4; ++mi)
      #pragma unroll
      for (int r = 0; r < 4; ++r) {
        int n = rb + mi * 16 + orow + r;
        if (n < N) outp[((size_t)n * T + t) * OUTD + oc] = acc[mi][ni][r] + bb;
      }
  }
}

// ---------------------------------------------------------------------------

extern "C" void kernel_launch(void* const* d_in, const int* in_sizes, int n_in,
                              void* d_out, int out_size, void* d_ws, size_t ws_size,
                              hipStream_t stream) {
  const float* x_seq = (const float*)d_in[0];
  const int*   eidx  = (const int*)d_in[1];
  const int*   erow  = eidx;          // sources
  const int*   ecol  = eidx + E;      // targets
  const float* W_gcn = (const float*)d_in[2];
  const float* b_gcn = (const float*)d_in[3];
  const float* W_ih  = (const float*)d_in[4];
  const float* W_hh  = (const float*)d_in[5];
  const float* b_ih  = (const float*)d_in[6];
  const float* b_hh  = (const float*)d_in[7];
  const float* W_fc  = (const float*)d_in[8];
  const float* b_fc  = (const float*)d_in[9];
  float* outp = (float*)d_out;

  char* base = (char*)d_ws;
  size_t o = 0;
  auto alloc = [&](size_t bytes) -> void* {
    void* p = base + o;
    o += (bytes + 255) & ~(size_t)255;
    return p;
  };
  int*   cnt      = (int*)  alloc((size_t)N * 4);
  int*   cursor   = (int*)  alloc((size_t)N * 4);
  int*   offv     = (int*)  alloc((size_t)(N + 1) * 4);
  int*   csum     = (int*)  alloc((size_t)(NCH + 1) * 4);
  int*   coff     = (int*)  alloc((size_t)(NCH + 1) * 4);
  float* dinv     = (float*)alloc((size_t)N * 4);
  int2*  csr      = (int2*) alloc((size_t)E * 8);
  _Float16* bt    = (_Float16*)alloc((size_t)G * 256 * 2);
  _Float16* bgT   = (_Float16*)alloc((size_t)H * H * 2);
  _Float16* wfc16 = (_Float16*)alloc((size_t)OUTD * H * 2);
  _Float16* xwA   = (_Float16*)alloc((size_t)N * TCA * H * 2);       // 64 MB
  _Float16* xwB   = (_Float16*)alloc((size_t)N * TCB * H * 2);       // 51 MB
  _Float16* emb_all= (_Float16*)alloc((size_t)(T * N + 128) * H * 2); // [T][N][H] + pad
  _Float16* h_all = (_Float16*)alloc((size_t)(T * N + 128) * H * 2);  // [T][N][H] + pad
  float* cbuf     = (float*)alloc((size_t)N * H * 4);
  (void)ws_size; (void)in_sizes; (void)n_in; (void)out_size;

  // only the small CSR counters need zeroing; h/c state handled by the
  // FIRST-step specialization; pad rows only affect discarded output rows.
  hipMemsetAsync(cnt,    0, (size_t)N * 4, stream);
  hipMemsetAsync(cursor, 0, (size_t)N * 4, stream);

  k_count<<<E / 256, 256, 0, stream>>>(ecol, cnt);
  k_dinv<<<(N + 255) / 256, 256, 0, stream>>>(cnt, dinv);
  k_chunk_sum<<<NCH, SCAN_CH, 0, stream>>>(cnt, csum);
  k_chunk_scan<<<1, 64, 0, stream>>>(csum, coff);
  k_scan_final<<<NCH, SCAN_CH, 0, stream>>>(cnt, coff, offv);
  k_fill<<<E / 256, 256, 0, stream>>>(erow, ecol, dinv, offv, cursor, csr);
  k_wprep_lstm<<<(G * 256) / 256, 256, 0, stream>>>(W_ih, W_hh, bt);
  k_wprep_gcn<<<(H * H) / 256, 256, 0, stream>>>(W_gcn, bgT);
  k_wprep_fc<<<(OUTD * H + 255) / 256, 256, 0, stream>>>(W_fc, wfc16);

  // all 9 GCN GEMMs in one dispatch (no LSTM dependence)
  k_gcn_all<<<dim3(NP / 128, T), 256, 0, stream>>>(x_seq, bgT, xwA, xwB);
  // aggregation in 2 t-chunk passes (at the random-gather ceiling)
  k_agg_chunk<TCA><<<N / 4, 256, 0, stream>>>(xwA, offv, (const long long*)csr,
                                              dinv, b_gcn, emb_all);
  k_agg_chunk<TCB><<<N / 4, 256, 0, stream>>>(xwB, offv, (const long long*)csr,
                                              dinv, b_gcn,
                                              emb_all + (size_t)TCA * N * H);

  // LSTM recurrence: gates+cell only (h_t -> plane t of h_all)
  for (int t = 0; t < T; ++t) {
    const _Float16* embt = emb_all + (size_t)t * N * H;
    const _Float16* hcur = (t == 0) ? h_all : h_all + (size_t)(t - 1) * N * H;
    _Float16* oH = h_all + (size_t)t * N * H;
    if (t == 0)
      k_gates_cell<true><<<GNWG, 256, 0, stream>>>(
          embt, hcur, bt, b_ih, b_hh, cbuf, oH);
    else
      k_gates_cell<false><<<GNWG, 256, 0, stream>>>(
          embt, hcur, bt, b_ih, b_hh, cbuf, oH);
  }
  // all 9 FC GEMMs in one dispatch
  k_fc_all<<<dim3((NP + 255) / 256, T), 256, 0, stream>>>(h_all, wfc16, b_fc, outp);
}

// Round 18
// 1169.191 us; speedup vs baseline: 1.0780x; 1.0150x over previous
//
#include <hip/hip_runtime.h>
#include <cstdint>
#include <cstddef>

// ---------------------------------------------------------------------------
// GCN(1 layer, sym-norm w/ self loops) -> LSTM(1 layer, T=9) -> FC, eval mode
// Round 18: LSTM cell state c stored fp16 (geometric-decay accumulation =>
// quantization error does NOT random-walk; steady-state dout ~1e-4, inside
// budget). Saves 230MB HBM across the 9 gates steps. Everything else
// unchanged from round 17.
// ---------------------------------------------------------------------------

constexpr int N    = 50000;
constexpr int NP   = 50048;  // padded to 128-row strips (391*128)
constexpr int E    = 1600000;
constexpr int T    = 9;
constexpr int H    = 128;    // F_IN == H == 128
constexpr int G    = 512;    // 4*H (gates i,f,g,o)
constexpr int OUTD = 32;
constexpr int TCA  = 5;      // agg chunk A: t = 0..4
constexpr int TCB  = 4;      // agg chunk B: t = 5..8

constexpr int SCAN_CH = 512;
constexpr int NCH = (N + SCAN_CH - 1) / SCAN_CH;   // 98

// gates grid: 391 row-strips x 4 col-quarters
constexpr int GNWG = (NP / 128) * 4;               // 1564
constexpr int GQQ  = GNWG / 8;                     // 195
constexpr int GRR  = GNWG % 8;                     // 4

typedef __attribute__((ext_vector_type(8))) _Float16 f16x8;
typedef __attribute__((ext_vector_type(4))) float f32x4;
typedef __attribute__((ext_vector_type(4))) _Float16 f16x4;

// async global->LDS, 16B per lane; LDS dest = wave-uniform base + lane*16
__device__ __forceinline__ void gll16(const void* g, void* l) {
  __builtin_amdgcn_global_load_lds(
      (const __attribute__((address_space(1))) void*)g,
      (__attribute__((address_space(3))) void*)l, 16, 0, 0);
}

// ---------------- degree / CSR build ----------------

__global__ void k_count(const int* __restrict__ col, int* __restrict__ cnt) {
  int e = blockIdx.x * 256 + threadIdx.x;
  if (e < E) atomicAdd(&cnt[col[e]], 1);
}

__global__ void k_dinv(const int* __restrict__ cnt, float* __restrict__ dinv) {
  int v = blockIdx.x * 256 + threadIdx.x;
  if (v < N) dinv[v] = rsqrtf((float)cnt[v] + 1.0f);   // +1 self loop
}

__global__ void k_chunk_sum(const int* __restrict__ cnt, int* __restrict__ csum) {
  __shared__ int sp[SCAN_CH / 64];
  int i = blockIdx.x * SCAN_CH + threadIdx.x;
  int v = (i < N) ? cnt[i] : 0;
  for (int off = 32; off > 0; off >>= 1) v += __shfl_down(v, off, 64);
  if ((threadIdx.x & 63) == 0) sp[threadIdx.x >> 6] = v;
  __syncthreads();
  if (threadIdx.x == 0) {
    int s = 0;
    #pragma unroll
    for (int w = 0; w < SCAN_CH / 64; ++w) s += sp[w];
    csum[blockIdx.x] = s;
  }
}

__global__ void k_chunk_scan(const int* __restrict__ csum, int* __restrict__ coff) {
  if (blockIdx.x == 0 && threadIdx.x == 0) {
    int run = 0;
    for (int b = 0; b < NCH; ++b) { coff[b] = run; run += csum[b]; }
    coff[NCH] = run;
  }
}

__global__ void k_scan_final(const int* __restrict__ cnt, const int* __restrict__ coff,
                             int* __restrict__ offv) {
  __shared__ int s[SCAN_CH];
  int tid = threadIdx.x;
  int i = blockIdx.x * SCAN_CH + tid;
  int v = (i < N) ? cnt[i] : 0;
  s[tid] = v;
  __syncthreads();
  for (int st = 1; st < SCAN_CH; st <<= 1) {
    int tv = (tid >= st) ? s[tid - st] : 0;
    __syncthreads();
    s[tid] += tv;
    __syncthreads();
  }
  if (i < N) offv[i] = coff[blockIdx.x] + s[tid] - v;   // exclusive
  if (blockIdx.x == 0 && tid == 0) offv[N] = coff[NCH];
}

// packed CSR entry: one 8B scatter per edge (halves write amplification)
__global__ void k_fill(const int* __restrict__ row, const int* __restrict__ col,
                       const float* __restrict__ dinv, const int* __restrict__ offv,
                       int* __restrict__ cursor, int2* __restrict__ csr) {
  int e = blockIdx.x * 256 + threadIdx.x;
  if (e >= E) return;
  int r = row[e], c = col[e];
  int p = atomicAdd(&cursor[c], 1);
  float nm = dinv[r] * dinv[c];
  csr[offv[c] + p] = make_int2(r, __builtin_bit_cast(int, nm));
}

// ---------------- weight prep (once per call) ----------------
// LSTM: bt[j][k] fp16 (j<512, k<256): k<128 -> W_ih[j][k], else W_hh[j][k-128]
__global__ void k_wprep_lstm(const float* __restrict__ Wih, const float* __restrict__ Whh,
                             _Float16* __restrict__ bt) {
  int idx = blockIdx.x * 256 + threadIdx.x;   // 512*256
  if (idx >= G * 256) return;
  int j = idx >> 8, k = idx & 255;
  float f = (k < H) ? Wih[j * H + k] : Whh[j * H + (k - H)];
  bt[idx] = (_Float16)f;
}

// GCN: bgT[j][k] = W_gcn[k][j]  (128x128) fp16
__global__ void k_wprep_gcn(const float* __restrict__ Wg, _Float16* __restrict__ bgT) {
  int idx = blockIdx.x * 256 + threadIdx.x;   // 128*128
  if (idx >= H * H) return;
  int j = idx >> 7, k = idx & 127;
  bgT[idx] = (_Float16)Wg[k * H + j];
}

// FC: wfc16[j][k] fp16 copy of W_fc (32x128)
__global__ void k_wprep_fc(const float* __restrict__ Wfc, _Float16* __restrict__ w16) {
  int idx = blockIdx.x * 256 + threadIdx.x;   // 32*128
  if (idx < OUTD * H) w16[idx] = (_Float16)Wfc[idx];
}

// ---------------- GCN GEMM (MFMA fp16), ALL timesteps ----------------
// Output into two chunk buffers: xwA [N][5*128] (t=0..4), xwB [N][4*128].
// grid (391, 9); block 256 thr = 4 waves (2x2) -> 128 rows x 128 cols.
__global__ __launch_bounds__(256) void k_gcn_all(const float* __restrict__ Xall,
                                                 const _Float16* __restrict__ BgT,
                                                 _Float16* __restrict__ xwA,
                                                 _Float16* __restrict__ xwB) {
  __shared__ _Float16 lsB[16384];   // [kb][j][g'] 16B granules, 32KB
  int t = blockIdx.y;
  const float* X = Xall + (size_t)t * N * H;
  _Float16* xw;
  int rs;
  if (t < TCA) { xw = xwA + t * H;         rs = TCA * H; }
  else         { xw = xwB + (t - TCA) * H; rs = TCB * H; }
  int tid = threadIdx.x;
  int lane = tid & 63, wid = tid >> 6;
  int wr = wid >> 1, wc = wid & 1;
  int rb = blockIdx.x * 128 + wr * 64;
  int cb = wc * 64;
  int lr = lane & 15;
  int g  = lane >> 4;

  #pragma unroll
  for (int i = 0; i < 8; ++i) {           // stage B: 2048 granules of 16B
    int c = i * 256 + tid;
    int kb = c >> 9, j = (c >> 2) & 127, gg = c & 3;
    f16x8 v = *(const f16x8*)&BgT[j * H + kb * 32 + gg * 8];
    int slot = gg ^ ((j >> 1) & 3);
    *(f16x8*)&lsB[kb * 4096 + j * 32 + slot * 8] = v;
  }
  __syncthreads();

  f32x4 acc[4][4];
  #pragma unroll
  for (int mi = 0; mi < 4; ++mi)
    #pragma unroll
    for (int ni = 0; ni < 4; ++ni) acc[mi][ni] = (f32x4)0.0f;

  #pragma unroll
  for (int kb = 0; kb < 4; ++kb) {
    f16x8 bfr[4];
    #pragma unroll
    for (int ni = 0; ni < 4; ++ni) {
      int j = cb + ni * 16 + lr;
      bfr[ni] = *(const f16x8*)&lsB[kb * 4096 + j * 32 + (g ^ ((j >> 1) & 3)) * 8];
    }
    #pragma unroll
    for (int mi = 0; mi < 4; ++mi) {
      int r = rb + mi * 16 + lr;
      r = r < N ? r : N - 1;                     // clamp (pad rows discarded)
      const float* ap = X + (size_t)r * H + kb * 32 + g * 8;
      float4 a0 = *(const float4*)ap;
      float4 a1 = *(const float4*)(ap + 4);
      f16x8 afr;
      afr[0] = (_Float16)a0.x; afr[1] = (_Float16)a0.y;
      afr[2] = (_Float16)a0.z; afr[3] = (_Float16)a0.w;
      afr[4] = (_Float16)a1.x; afr[5] = (_Float16)a1.y;
      afr[6] = (_Float16)a1.z; afr[7] = (_Float16)a1.w;
      #pragma unroll
      for (int ni = 0; ni < 4; ++ni)
        acc[mi][ni] = __builtin_amdgcn_mfma_f32_16x16x32_f16(afr, bfr[ni], acc[mi][ni], 0, 0, 0);
    }
  }
  int orow = (lane >> 4) * 4;
  #pragma unroll
  for (int mi = 0; mi < 4; ++mi)
    #pragma unroll
    for (int ni = 0; ni < 4; ++ni)
      #pragma unroll
      for (int r = 0; r < 4; ++r) {
        int n = rb + mi * 16 + orow + r;
        if (n < N) xw[(size_t)n * rs + cb + ni * 16 + lr] = (_Float16)acc[mi][ni][r];
      }
}

// ---------------- aggregation, one t-chunk per dispatch ----------------
// Wave per vertex; two 32-lane halves process even/odd edges, 2 edges per
// iteration (2*TC loads in flight). Edge meta read once per pass (NT).
// Source region [s][TC*H] contiguous. At the random-gather fabric ceiling.
template<int TC>
__global__ __launch_bounds__(256) void k_agg_chunk(const _Float16* __restrict__ xw,
                                                   const int* __restrict__ offv,
                                                   const long long* __restrict__ csr,
                                                   const float* __restrict__ dinv,
                                                   const float* __restrict__ bg,
                                                   _Float16* __restrict__ embc) {
  constexpr int RS = TC * H;
  int wid = threadIdx.x >> 6, lane = threadIdx.x & 63;
  int v = blockIdx.x * 4 + wid;          // N % 4 == 0
  int half = lane >> 5, sl = lane & 31;
  int c0 = sl * 4;
  float acc[TC][4];
  #pragma unroll
  for (int t = 0; t < TC; ++t) {
    acc[t][0] = 0.f; acc[t][1] = 0.f; acc[t][2] = 0.f; acc[t][3] = 0.f;
  }
  if (half == 0) {                       // self term once
    float dv = dinv[v];
    float w = dv * dv;
    const _Float16* xp = xw + (size_t)v * RS + c0;
    #pragma unroll
    for (int t = 0; t < TC; ++t) {
      f16x4 xs = *(const f16x4*)(xp + t * H);
      acc[t][0] = (float)xs.x * w; acc[t][1] = (float)xs.y * w;
      acc[t][2] = (float)xs.z * w; acc[t][3] = (float)xs.w * w;
    }
  }
  int e0 = offv[v], e1 = offv[v + 1];
  int e = e0 + half;
  for (; e + 2 < e1; e += 4) {           // 2 edges in flight per half
    long long r0 = __builtin_nontemporal_load(&csr[e]);
    long long r1 = __builtin_nontemporal_load(&csr[e + 2]);
    int s0 = (int)(r0 & 0xffffffffLL);
    int s1 = (int)(r1 & 0xffffffffLL);
    float m0 = __builtin_bit_cast(float, (int)(r0 >> 32));
    float m1 = __builtin_bit_cast(float, (int)(r1 >> 32));
    const _Float16* xp0 = xw + (size_t)s0 * RS + c0;
    const _Float16* xp1 = xw + (size_t)s1 * RS + c0;
    f16x4 xa[TC], xb[TC];
    #pragma unroll
    for (int t = 0; t < TC; ++t) {
      xa[t] = *(const f16x4*)(xp0 + t * H);
      xb[t] = *(const f16x4*)(xp1 + t * H);
    }
    #pragma unroll
    for (int t = 0; t < TC; ++t) {
      acc[t][0] = fmaf((float)xa[t].x, m0, acc[t][0]);
      acc[t][1] = fmaf((float)xa[t].y, m0, acc[t][1]);
      acc[t][2] = fmaf((float)xa[t].z, m0, acc[t][2]);
      acc[t][3] = fmaf((float)xa[t].w, m0, acc[t][3]);
      acc[t][0] = fmaf((float)xb[t].x, m1, acc[t][0]);
      acc[t][1] = fmaf((float)xb[t].y, m1, acc[t][1]);
      acc[t][2] = fmaf((float)xb[t].z, m1, acc[t][2]);
      acc[t][3] = fmaf((float)xb[t].w, m1, acc[t][3]);
    }
  }
  if (e < e1) {                          // tail edge
    long long r0 = __builtin_nontemporal_load(&csr[e]);
    int s0 = (int)(r0 & 0xffffffffLL);
    float m0 = __builtin_bit_cast(float, (int)(r0 >> 32));
    const _Float16* xp0 = xw + (size_t)s0 * RS + c0;
    #pragma unroll
    for (int t = 0; t < TC; ++t) {
      f16x4 x = *(const f16x4*)(xp0 + t * H);
      acc[t][0] = fmaf((float)x.x, m0, acc[t][0]);
      acc[t][1] = fmaf((float)x.y, m0, acc[t][1]);
      acc[t][2] = fmaf((float)x.z, m0, acc[t][2]);
      acc[t][3] = fmaf((float)x.w, m0, acc[t][3]);
    }
  }
  #pragma unroll
  for (int t = 0; t < TC; ++t) {
    acc[t][0] += __shfl_xor(acc[t][0], 32, 64);
    acc[t][1] += __shfl_xor(acc[t][1], 32, 64);
    acc[t][2] += __shfl_xor(acc[t][2], 32, 64);
    acc[t][3] += __shfl_xor(acc[t][3], 32, 64);
  }
  if (half == 0) {
    float4 bb = *(const float4*)&bg[c0];
    #pragma unroll
    for (int t = 0; t < TC; ++t) {
      f16x4 ov;
      ov.x = (_Float16)fmaxf(acc[t][0] + bb.x, 0.f);
      ov.y = (_Float16)fmaxf(acc[t][1] + bb.y, 0.f);
      ov.z = (_Float16)fmaxf(acc[t][2] + bb.z, 0.f);
      ov.w = (_Float16)fmaxf(acc[t][3] + bb.w, 0.f);
      __builtin_nontemporal_store(ov,
          (f16x4*)&embc[(size_t)t * N * H + (size_t)v * H + c0]);
    }
  }
}

// ---------------- fused gates GEMM + LSTM cell (fp16, deep pipeline) --------
// 256 thr = 4 waves (wr x wc = 2x2). Block tile: 128 rows x 128 logical cols
// (jj = gate*32 + wc*16 + lr -> global j = gate*128 + ch0 + ...), so each wave
// holds (i,f,g,o) of the same (row, channel): cell update in-register.
// K: 8 kblocks of 32 fp16 — kb 0..3 stage emb_t, kb 4..7 stage h_{t-1}.
// 3 x 16KB LDS buffers, 2-deep prefetch, counted vmcnt (round 17).
// c state fp16 (geometric-decay accumulation -> quantization error bounded).
// h_t written to its own plane h_all[t][N][128] (plane != hcur: no race).
template<bool FIRST>
__global__ __launch_bounds__(256) void k_gates_cell(const _Float16* __restrict__ embt,
                                                    const _Float16* __restrict__ hcur,
                                                    const _Float16* __restrict__ Bt,
                                                    const float* __restrict__ bih,
                                                    const float* __restrict__ bhh,
                                                    _Float16* __restrict__ cb16,
                                                    _Float16* __restrict__ oH) {
  __shared__ _Float16 ls[3][8192];   // 3 x 16KB: [A 8KB | B 8KB]
  const int tid = threadIdx.x;
  const int lane = tid & 63, wid = tid >> 6;
  const int wr = wid >> 1, wc = wid & 1;
  const int lr = lane & 15;
  const int g  = lane >> 4;                 // k granule 0..3 (8 fp16 each)

  // bijective XCD-chunk swizzle (m204)
  int xcd = blockIdx.x & 7, loc = blockIdx.x >> 3;
  int wgid = (xcd < GRR ? xcd * (GQQ + 1) : GRR * (GQQ + 1) + (xcd - GRR) * GQQ) + loc;
  const int rb  = (wgid >> 2) * 128;
  const int ch0 = (wgid & 3) * 32;

  f32x4 acc[4][4];
  #pragma unroll
  for (int mi = 0; mi < 4; ++mi)
    #pragma unroll
    for (int ni = 0; ni < 4; ++ni) acc[mi][ni] = (f32x4)0.0f;

  // stage one 16KB k-block tile: EXACTLY 4 global_load_lds per thread
  auto stage = [&](int buf, int kb) {
    const _Float16* srcA = (kb < 4) ? embt : hcur;   // both [N(P)][128]
    int koA = (kb & 3) * 32;
    int koB = kb * 32;
    _Float16* lb = &ls[buf][0];
    #pragma unroll
    for (int i = 0; i < 2; ++i) {
      int c = i * 256 + tid;               // 16B chunk id 0..511
      int row = c >> 2, slot = c & 3;
      int g3 = slot ^ ((row >> 1) & 3);    // pre-swizzled global granule
      size_t ga = (size_t)(rb + row) * H + koA + g3 * 8;
      gll16(srcA + ga, lb + c * 8);
      int j = (row >> 5) * 128 + ch0 + (row & 31);
      size_t gb = (size_t)j * 256 + koB + g3 * 8;
      gll16(Bt + gb, lb + 4096 + c * 8);
    }
  };

  auto compute = [&](int buf) {
    const _Float16* lb = &ls[buf][0];
    f16x8 bfr[4];
    #pragma unroll
    for (int ni = 0; ni < 4; ++ni) {
      int jj = ni * 32 + wc * 16 + lr;
      bfr[ni] = *(const f16x8*)(lb + 4096 + jj * 32 + (g ^ ((jj >> 1) & 3)) * 8);
    }
    #pragma unroll
    for (int mi = 0; mi < 4; ++mi) {
      int rr = wr * 64 + mi * 16 + lr;
      f16x8 afr = *(const f16x8*)(lb + rr * 32 + (g ^ ((rr >> 1) & 3)) * 8);
      #pragma unroll
      for (int ni = 0; ni < 4; ++ni)
        acc[mi][ni] = __builtin_amdgcn_mfma_f32_16x16x32_f16(afr, bfr[ni], acc[mi][ni], 0, 0, 0);
    }
  };

  const int kbs = FIRST ? 4 : 8;            // t=0: h==0, skip upper K half
  stage(0, 0);
  stage(1, 1);
  for (int kb = 0; kb < kbs; ++kb) {
    if (kb + 1 < kbs) asm volatile("s_waitcnt vmcnt(4)" ::: "memory");
    else              asm volatile("s_waitcnt vmcnt(0)" ::: "memory");
    __builtin_amdgcn_s_barrier();
    asm volatile("" ::: "memory");          // no ds_read hoisting above barrier
    if (kb + 2 < kbs) stage((kb + 2) % 3, kb + 2);
    compute(kb % 3);
  }

  int ch = ch0 + wc * 16 + lr;
  float bi_ = bih[ch]       + bhh[ch];
  float bf_ = bih[128 + ch] + bhh[128 + ch];
  float bg_ = bih[256 + ch] + bhh[256 + ch];
  float bo_ = bih[384 + ch] + bhh[384 + ch];
  int orow = (lane >> 4) * 4;
  int rbw = rb + wr * 64;
  #pragma unroll
  for (int mi = 0; mi < 4; ++mi) {
    #pragma unroll
    for (int r = 0; r < 4; ++r) {
      int n = rbw + mi * 16 + orow + r;
      if (n >= N) continue;
      float gi = acc[mi][0][r] + bi_;
      float gf = acc[mi][1][r] + bf_;
      float gg = acc[mi][2][r] + bg_;
      float go = acc[mi][3][r] + bo_;
      float si = 1.f / (1.f + expf(-gi));
      float sf = 1.f / (1.f + expf(-gf));
      float so = 1.f / (1.f + expf(-go));
      float tg = tanhf(gg);
      size_t ci = (size_t)n * H + ch;
      float cn = FIRST ? si * tg : fmaf(sf, (float)cb16[ci], si * tg);
      cb16[ci] = (_Float16)cn;
      float hn = so * tanhf(cn);
      oH[ci] = (_Float16)hn;
    }
  }
}

// ---------------- FC (MFMA), ALL timesteps in one dispatch ----------------
// grid (196, 9). h fp16 from h_all plane t; Wfc fp16 [32][128]. Wave = 64
// rows x 32 cols (mi=4, ni=2, 4 kblocks -> 32 MFMAs). 4 waves = 256 rows.
__global__ __launch_bounds__(256) void k_fc_all(const _Float16* __restrict__ h_all,
                                                const _Float16* __restrict__ w16,
                                                const float* __restrict__ bfc,
                                                float* __restrict__ outp) {
  int t = blockIdx.y;
  const _Float16* Hc = h_all + (size_t)t * N * H;
  int lane = threadIdx.x & 63, wid = threadIdx.x >> 6;
  int rb = blockIdx.x * 256 + wid * 64;
  int lr = lane & 15, g = lane >> 4;
  f32x4 acc[4][2];
  #pragma unroll
  for (int mi = 0; mi < 4; ++mi) { acc[mi][0] = (f32x4)0.0f; acc[mi][1] = (f32x4)0.0f; }

  #pragma unroll
  for (int kb = 0; kb < 4; ++kb) {
    int ko = kb * 32 + g * 8;
    f16x8 bfr[2];
    #pragma unroll
    for (int ni = 0; ni < 2; ++ni)
      bfr[ni] = *(const f16x8*)&w16[(ni * 16 + lr) * H + ko];
    #pragma unroll
    for (int mi = 0; mi < 4; ++mi) {
      int n = rb + mi * 16 + lr;
      n = n < N ? n : N - 1;               // clamp (pad rows discarded)
      f16x8 afr = *(const f16x8*)&Hc[(size_t)n * H + ko];
      #pragma unroll
      for (int ni = 0; ni < 2; ++ni)
        acc[mi][ni] = __builtin_amdgcn_mfma_f32_16x16x32_f16(afr, bfr[ni], acc[mi][ni], 0, 0, 0);
    }
  }
  int orow = g * 4;
  #pragma unroll
  for (int ni = 0; ni < 2; ++ni) {
    int oc = ni * 16 + lr;
    float bb = bfc[oc];
    #pragma unroll
    for (int mi = 0; mi < 4; ++mi)
      #pragma unroll
      for (int r = 0; r < 4; ++r) {
        int n = rb + mi * 16 + orow + r;
        if (n < N) outp[((size_t)n * T + t) * OUTD + oc] = acc[mi][ni][r] + bb;
      }
  }
}

// ---------------------------------------------------------------------------

extern "C" void kernel_launch(void* const* d_in, const int* in_sizes, int n_in,
                              void* d_out, int out_size, void* d_ws, size_t ws_size,
                              hipStream_t stream) {
  const float* x_seq = (const float*)d_in[0];
  const int*   eidx  = (const int*)d_in[1];
  const int*   erow  = eidx;          // sources
  const int*   ecol  = eidx + E;      // targets
  const float* W_gcn = (const float*)d_in[2];
  const float* b_gcn = (const float*)d_in[3];
  const float* W_ih  = (const float*)d_in[4];
  const float* W_hh  = (const float*)d_in[5];
  const float* b_ih  = (const float*)d_in[6];
  const float* b_hh  = (const float*)d_in[7];
  const float* W_fc  = (const float*)d_in[8];
  const float* b_fc  = (const float*)d_in[9];
  float* outp = (float*)d_out;

  char* base = (char*)d_ws;
  size_t o = 0;
  auto alloc = [&](size_t bytes) -> void* {
    void* p = base + o;
    o += (bytes + 255) & ~(size_t)255;
    return p;
  };
  int*   cnt      = (int*)  alloc((size_t)N * 4);
  int*   cursor   = (int*)  alloc((size_t)N * 4);
  int*   offv     = (int*)  alloc((size_t)(N + 1) * 4);
  int*   csum     = (int*)  alloc((size_t)(NCH + 1) * 4);
  int*   coff     = (int*)  alloc((size_t)(NCH + 1) * 4);
  float* dinv     = (float*)alloc((size_t)N * 4);
  int2*  csr      = (int2*) alloc((size_t)E * 8);
  _Float16* bt    = (_Float16*)alloc((size_t)G * 256 * 2);
  _Float16* bgT   = (_Float16*)alloc((size_t)H * H * 2);
  _Float16* wfc16 = (_Float16*)alloc((size_t)OUTD * H * 2);
  _Float16* xwA   = (_Float16*)alloc((size_t)N * TCA * H * 2);       // 64 MB
  _Float16* xwB   = (_Float16*)alloc((size_t)N * TCB * H * 2);       // 51 MB
  _Float16* emb_all= (_Float16*)alloc((size_t)(T * N + 128) * H * 2); // [T][N][H] + pad
  _Float16* h_all = (_Float16*)alloc((size_t)(T * N + 128) * H * 2);  // [T][N][H] + pad
  _Float16* cb16  = (_Float16*)alloc((size_t)N * H * 2);              // fp16 cell state
  (void)ws_size; (void)in_sizes; (void)n_in; (void)out_size;

  // only the small CSR counters need zeroing; h/c state handled by the
  // FIRST-step specialization; pad rows only affect discarded output rows.
  hipMemsetAsync(cnt,    0, (size_t)N * 4, stream);
  hipMemsetAsync(cursor, 0, (size_t)N * 4, stream);

  k_count<<<E / 256, 256, 0, stream>>>(ecol, cnt);
  k_dinv<<<(N + 255) / 256, 256, 0, stream>>>(cnt, dinv);
  k_chunk_sum<<<NCH, SCAN_CH, 0, stream>>>(cnt, csum);
  k_chunk_scan<<<1, 64, 0, stream>>>(csum, coff);
  k_scan_final<<<NCH, SCAN_CH, 0, stream>>>(cnt, coff, offv);
  k_fill<<<E / 256, 256, 0, stream>>>(erow, ecol, dinv, offv, cursor, csr);
  k_wprep_lstm<<<(G * 256) / 256, 256, 0, stream>>>(W_ih, W_hh, bt);
  k_wprep_gcn<<<(H * H) / 256, 256, 0, stream>>>(W_gcn, bgT);
  k_wprep_fc<<<(OUTD * H + 255) / 256, 256, 0, stream>>>(W_fc, wfc16);

  // all 9 GCN GEMMs in one dispatch (no LSTM dependence)
  k_gcn_all<<<dim3(NP / 128, T), 256, 0, stream>>>(x_seq, bgT, xwA, xwB);
  // aggregation in 2 t-chunk passes (at the random-gather ceiling)
  k_agg_chunk<TCA><<<N / 4, 256, 0, stream>>>(xwA, offv, (const long long*)csr,
                                              dinv, b_gcn, emb_all);
  k_agg_chunk<TCB><<<N / 4, 256, 0, stream>>>(xwB, offv, (const long long*)csr,
                                              dinv, b_gcn,
                                              emb_all + (size_t)TCA * N * H);

  // LSTM recurrence: gates+cell only (h_t -> plane t of h_all)
  for (int t = 0; t < T; ++t) {
    const _Float16* embt = emb_all + (size_t)t * N * H;
    const _Float16* hcur = (t == 0) ? h_all : h_all + (size_t)(t - 1) * N * H;
    _Float16* oH = h_all + (size_t)t * N * H;
    if (t == 0)
      k_gates_cell<true><<<GNWG, 256, 0, stream>>>(
          embt, hcur, bt, b_ih, b_hh, cb16, oH);
    else
      k_gates_cell<false><<<GNWG, 256, 0, stream>>>(
          embt, hcur, bt, b_ih, b_hh, cb16, oH);
  }
  // all 9 FC GEMMs in one dispatch
  k_fc_all<<<dim3((NP + 255) / 256, T), 256, 0, stream>>>(h_all, wfc16, b_fc, outp);
}